// Round 6
// baseline (989.108 us; speedup 1.0000x reference)
//
#include <hip/hip_runtime.h>

#define LOG2E 1.4426950408889634f

typedef float  f32x4 __attribute__((ext_vector_type(4)));
typedef float  f32x2 __attribute__((ext_vector_type(2)));
typedef int    i32x4 __attribute__((ext_vector_type(4)));
typedef short  s16x8 __attribute__((ext_vector_type(8)));
typedef unsigned long long u64x2 __attribute__((ext_vector_type(2)));

static __device__ __forceinline__ float exp2_fast(float x) {
#if __has_builtin(__builtin_amdgcn_exp2f)
    return __builtin_amdgcn_exp2f(x);
#else
    return exp2f(x);
#endif
}
static __device__ __forceinline__ unsigned short bf16_rne(float f) {
    unsigned u = __float_as_uint(f);
    u += 0x7FFFu + ((u >> 16) & 1u);
    return (unsigned short)(u >> 16);
}
// 1-bit signed bitfield extract -> 0 or 0xFFFFFFFF
static __device__ __forceinline__ int sbfe1(unsigned w, int pos) {
#if __has_builtin(__builtin_amdgcn_sbfe)
    return __builtin_amdgcn_sbfe((int)w, pos, 1);
#else
    return (int)(w << (31 - pos)) >> 31;
#endif
}
// pack hi16(u0) | hi16(u1)<<16 in one v_perm
static __device__ __forceinline__ unsigned pack_hi16(unsigned u1, unsigned u0) {
#if __has_builtin(__builtin_amdgcn_perm)
    return __builtin_amdgcn_perm(u1, u0, 0x07060302u);
#else
    return (u0 >> 16) | (u1 & 0xFFFF0000u);
#endif
}

#define GRID_BLOCKS 512u

// ---------------------------------------------------------------------------
// Software grid barrier (persistent-kernel pattern; what cg::grid.sync() is,
// minus the cooperative-launch API that graph capture rejects).
// Monotonic per-sync counters (zeroed by captured hipMemsetAsync each replay).
// Residency of all 512 blocks guaranteed by __launch_bounds__(256,2):
// 2 blocks/CU x 256 CUs, LDS 34KB <= 80KB, VGPR <= 256.
// ---------------------------------------------------------------------------
static __device__ __forceinline__ void grid_sync(unsigned* cnt) {
    __syncthreads();
    if (threadIdx.x == 0) {
        __threadfence();                     // release (agent scope: L2 wb/inv)
        atomicAdd(cnt, 1u);
        while (__hip_atomic_load(cnt, __ATOMIC_ACQUIRE,
                                 __HIP_MEMORY_SCOPE_AGENT) < GRID_BLOCKS)
            __builtin_amdgcn_s_sleep(2);
    }
    __syncthreads();
    __threadfence();                         // acquire for all lanes
}

// ---------------------------------------------------------------------------
// Phase 0: adj -> bitmask, x -> bf16, W -> bf16 transposed, Mx init.
// ---------------------------------------------------------------------------
static __device__ __forceinline__ void do_prep(
    int blk, int tid,
    const float* __restrict__ xf, const int* __restrict__ adj,
    const float* __restrict__ W0, const float* __restrict__ W1,
    const float* __restrict__ W2,
    unsigned short* __restrict__ xc, unsigned long long* __restrict__ bits,
    unsigned short* __restrict__ W0t, unsigned short* __restrict__ W1t,
    unsigned short* __restrict__ W2t, unsigned* __restrict__ MxU)
{
    const int w = tid >> 6, lane = tid & 63;
    for (int b = blk; b < 16384; b += 512) {     // adj -> bits, 1024 elem/unit
        const int base = b * 1024 + w * 256;
        unsigned long long m[4];
#pragma unroll
        for (int r = 0; r < 4; ++r)
            m[r] = __ballot(adj[base + r * 64 + lane] != 0);
        if (lane == 0) {
            u64x2 lo = {m[0], m[1]}, hi = {m[2], m[3]};
            *(u64x2*)(bits + (base >> 6))     = lo;
            *(u64x2*)(bits + (base >> 6) + 2) = hi;
        }
    }
    for (int b = blk; b < 2048; b += 512) {      // x f32 -> bf16
        int i = b * 256 + tid;
        xc[i] = bf16_rne(xf[i]);
    }
    if (blk < 449) {                             // W transpose + Mx init
        int gid = blk * 256 + tid;
        if (gid < 32768) {                       // W0: (4,128,64)
            int h = gid >> 13, d = (gid >> 6) & 127, o = gid & 63;
            W0t[(h * 64 + o) * 128 + d] = bf16_rne(W0[gid]);
        } else if (gid < 98304) {                // W1: (4,256,64)
            int g = gid - 32768;
            int h = g >> 14, d = (g >> 6) & 255, o = g & 63;
            W1t[(h * 64 + o) * 256 + d] = bf16_rne(W1[g]);
        } else if (gid < 114688) {               // W2: (1,256,64)
            int g = gid - 98304;
            int d = g >> 6, o = g & 63;
            W2t[o * 256 + d] = bf16_rne(W2[g]);
        } else if (gid < 114700) {               // Mx[12] = encoded -inf
            MxU[gid - 114688] = 0x007FFFFFu;
        }
    }
}

// ---------------------------------------------------------------------------
// Phase G: h = X @ W (MFMA 16x16x32 bf16) -> hT[h][o][n] (bf16),
// fused el2/er2 and per-head max of er2 via encoded atomicMax.
// 64 rows per block (4 waves x 16). Active blocks: 64*H.
// ---------------------------------------------------------------------------
static __device__ __forceinline__ void do_gemm(
    int blk, int tid, int H,
    const unsigned short* __restrict__ X, int K,
    const unsigned short* __restrict__ Wt, const float* __restrict__ a,
    unsigned short* __restrict__ hT,
    float* __restrict__ el2, float* __restrict__ er2,
    unsigned* __restrict__ MxU)
{
    if (blk >= 64 * H) return;
    const int h = blk >> 6, bx = blk & 63;
    const int lane = tid & 63, w = tid >> 6;
    const int c = lane & 15, q = lane >> 4;
    const int nb = bx * 64 + w * 16;
    const unsigned short* xrow = X + (size_t)(nb + c) * K + q * 8;
    const unsigned short* wb   = Wt + ((size_t)h * 64 + c) * K + q * 8;

    f32x4 acc[4] = {{0,0,0,0},{0,0,0,0},{0,0,0,0},{0,0,0,0}};
    for (int kk = 0; kk < K; kk += 32) {
        s16x8 af = *(const s16x8*)(xrow + kk);
#pragma unroll
        for (int j = 0; j < 4; ++j) {
            s16x8 bf = *(const s16x8*)(wb + (size_t)(j * 16) * K + kk);
            acc[j] = __builtin_amdgcn_mfma_f32_16x16x32_bf16(af, bf, acc[j], 0, 0, 0);
        }
    }
    // C/D layout: col = lane&15, row = q*4 + reg  ->  hT[h][o][n]
#pragma unroll
    for (int j = 0; j < 4; ++j) {
        unsigned d0 = (unsigned)bf16_rne(acc[j][0]) | ((unsigned)bf16_rne(acc[j][1]) << 16);
        unsigned d1 = (unsigned)bf16_rne(acc[j][2]) | ((unsigned)bf16_rne(acc[j][3]) << 16);
        unsigned short* dst = hT + ((size_t)h * 64 + j * 16 + c) * 4096 + nb + q * 4;
        ((unsigned*)dst)[0] = d0;
        ((unsigned*)dst)[1] = d1;
    }
    const float* ab = a + h * 128;
    float elr[4] = {0,0,0,0}, err[4] = {0,0,0,0};
#pragma unroll
    for (int j = 0; j < 4; ++j) {
        float al = ab[j * 16 + c];
        float ar = ab[64 + j * 16 + c];
#pragma unroll
        for (int r = 0; r < 4; ++r) {
            elr[r] = fmaf(al, acc[j][r], elr[r]);
            err[r] = fmaf(ar, acc[j][r], err[r]);
        }
    }
#pragma unroll
    for (int m = 1; m <= 8; m <<= 1) {
#pragma unroll
        for (int r = 0; r < 4; ++r) {
            elr[r] += __shfl_xor(elr[r], m, 64);
            err[r] += __shfl_xor(err[r], m, 64);
        }
    }
    if (c == 0) {
#pragma unroll
        for (int r = 0; r < 4; ++r) {
            int n = nb + q * 4 + r;
            el2[h * 4096 + n] = elr[r] * LOG2E;
            er2[h * 4096 + n] = err[r] * LOG2E;
        }
    }
    float mm = fmaxf(fmaxf(err[0], err[1]), fmaxf(err[2], err[3]));
    mm = fmaxf(mm, __shfl_xor(mm, 16, 64));
    mm = fmaxf(mm, __shfl_xor(mm, 32, 64));
    if (lane == 0) {
        unsigned u = __float_as_uint(mm * LOG2E);
        unsigned key = (u & 0x80000000u) ? ~u : (u | 0x80000000u);
        atomicMax(MxU + h, key);
    }
}

// ---------------------------------------------------------------------------
// Phase A: fused masked-softmax attention, factorized exp2.
//   p[n][m] = max(Al[n]*Ar[m], Bl[n]*Br[m]) & adjbit      (p <= 1)
// SETS row-sets of 64 q-rows share each staged 64x128 key tile. Double-
// buffered global_load_lds staging (pre-swizzled source), one barrier/tile.
// ---------------------------------------------------------------------------
template <int SETS>
static __device__ __forceinline__ void do_att(
    int bx, int h, int ks, int tid,
    unsigned short (&ldsH)[2][64 * 128], float (&ldsE)[2][2][128],
    const unsigned short* __restrict__ hT,
    const float* __restrict__ el2g, const float* __restrict__ er2g,
    const unsigned* __restrict__ MxU,
    const unsigned long long* __restrict__ bits,
    float* __restrict__ accP, float* __restrict__ lP,
    int H, int KPS, int HO)
{
    const int lane = tid & 63, w = tid >> 6;
    const int c = lane & 15, q = lane >> 4, q8 = q * 8;
    const int nb = bx * (64 * SETS) + w * 16;

    unsigned kM = MxU[h];
    float M2 = __uint_as_float((kM & 0x80000000u) ? (kM & 0x7FFFFFFFu) : ~kM);

    f32x2 Av[SETS], Bv[SETS];
    const char* bitrow[SETS];
#pragma unroll
    for (int s = 0; s < SETS; ++s) {
        int rowA = nb + s * 64 + c;
        float e2 = el2g[h * 4096 + rowA];
        float xx = e2 + M2;
        float C2 = fmaxf(xx, 0.2f * xx);     // C2 >= all scores of this row
        float Al = exp2_fast(xx - C2);
        float Bl = exp2_fast(fmaf(0.2f, xx, -C2));
        Av[s] = (f32x2){Al, Al};
        Bv[s] = (f32x2){Bl, Bl};
        bitrow[s] = (const char*)bits + (size_t)rowA * 512 + (size_t)(KPS >> 3) * ks;
    }

    const unsigned short* hTh = hT + (size_t)h * 64 * 4096;
    const float* erh = er2g + h * 4096;
    const int tiles = KPS >> 7;
    const int kbase = ks * KPS;
    const int colE = tid & 127, hiE = tid >> 7;  // ldsE fill: 1 exp2/thread

    // DMA stage: LDS dest linear in lane; swizzle applied on the GLOBAL src
    // address (m173). Tile = 64 rows x 16 groups of 16B; group g at g^(o&7).
    auto STAGE = [&](int buf, int mabs_) {
#pragma unroll
        for (int i = 0; i < 4; ++i) {
            int cidx = i * 256 + tid;
            int o = cidx >> 4, g = cidx & 15;
            const unsigned short* sp =
                hTh + (size_t)o * 4096 + mabs_ + ((g ^ (o & 7)) << 3);
            unsigned short* dp = &ldsH[buf][(i * 256 + (tid & ~63)) << 3];
            __builtin_amdgcn_global_load_lds(
                (const __attribute__((address_space(1))) void*)sp,
                (__attribute__((address_space(3))) void*)dp, 16, 0, 0);
        }
    };

    s16x8 ones = {0,0,0,0,0,0,0,0};
    if (c == 0) {
#pragma unroll
        for (int i = 0; i < 8; ++i) ones[i] = (short)0x3F80;   // bf16 1.0, col 0
    }
    f32x4 acc[SETS][4];
    f32x4 accl[SETS];
#pragma unroll
    for (int s = 0; s < SETS; ++s) {
        accl[s] = (f32x4){0,0,0,0};
#pragma unroll
        for (int j = 0; j < 4; ++j) acc[s][j] = (f32x4){0,0,0,0};
    }

    // ---- prologue: stage tile 0 (DMA + column factors + bits) ----
    STAGE(0, kbase);
    {
        float ee = erh[kbase + colE] - M2;
        float xin = hiE ? 0.2f * ee : ee;
        ldsE[0][hiE][colE] = exp2_fast(xin);
    }
    i32x4 bA[SETS];
#pragma unroll
    for (int s = 0; s < SETS; ++s) bA[s] = *(const i32x4*)(bitrow[s]);
    __syncthreads();                         // drains DMA (vmcnt 0)

    for (int t = 0; t < tiles; ++t) {
        const int cur = t & 1, nxt = cur ^ 1;
        const bool more = (t + 1 < tiles);
        const unsigned short* Hc = ldsH[cur];
        const float* EcA = ldsE[cur][0];
        const float* EcB = ldsE[cur][1];

        float ern = 0.f;
        if (more) {
            const int mn = kbase + (t + 1) * 128;
            STAGE(nxt, mn);                  // async, drains at the barrier
            ern = erh[mn + colE];
        }
        int bw[SETS][4];
#pragma unroll
        for (int s = 0; s < SETS; ++s) {
            bw[s][0] = bA[s][0]; bw[s][1] = bA[s][1];
            bw[s][2] = bA[s][2]; bw[s][3] = bA[s][3];
        }
        if (more) {
#pragma unroll
            for (int s = 0; s < SETS; ++s)
                bA[s] = *(const i32x4*)(bitrow[s] + (t + 1) * 16);
        }

#pragma unroll
        for (int cc = 0; cc < 4; ++cc) {
            const int kl = cc * 32 + q8;
            const f32x4* eap = (const f32x4*)(EcA + kl);
            const f32x4* ebp = (const f32x4*)(EcB + kl);
            f32x4 eA0 = eap[0], eA1 = eap[1];      // Ar for 8 cols
            f32x4 eB0 = ebp[0], eB1 = ebp[1];      // Br for 8 cols
            const int klx = kl ^ ((c & 7) << 3);
            const unsigned short* lb = Hc + c * 128 + klx;
            s16x8 bf[4];
#pragma unroll
            for (int j = 0; j < 4; ++j)
                bf[j] = *(const s16x8*)(lb + (size_t)(j * 16) * 128);

            s16x8 af[SETS];
#pragma unroll
            for (int s = 0; s < SETS; ++s) {
                const unsigned word = (unsigned)bw[s][cc];
                unsigned pd[4];
#pragma unroll
                for (int jj = 0; jj < 4; ++jj) {
                    f32x2 ea = (jj == 0) ? eA0.xy : (jj == 1) ? eA0.zw
                             : (jj == 2) ? eA1.xy : eA1.zw;
                    f32x2 eb = (jj == 0) ? eB0.xy : (jj == 1) ? eB0.zw
                             : (jj == 2) ? eB1.xy : eB1.zw;
                    f32x2 pa = Av[s] * ea;         // v_pk_mul_f32
                    f32x2 pb = Bv[s] * eb;         // v_pk_mul_f32
                    float p0 = fmaxf(pa.x, pb.x);
                    float p1 = fmaxf(pa.y, pb.y);
                    unsigned u0 = __float_as_uint(p0) & (unsigned)sbfe1(word, q8 + 2 * jj);
                    unsigned u1 = __float_as_uint(p1) & (unsigned)sbfe1(word, q8 + 2 * jj + 1);
                    pd[jj] = pack_hi16(u1, u0);    // truncate-pack 2 bf16
                }
                union { unsigned u[4]; s16x8 s8; } afu;
                afu.u[0] = pd[0]; afu.u[1] = pd[1];
                afu.u[2] = pd[2]; afu.u[3] = pd[3];
                af[s] = afu.s8;
            }
            __builtin_amdgcn_s_setprio(1);
#pragma unroll
            for (int s = 0; s < SETS; ++s) {
#pragma unroll
                for (int j = 0; j < 4; ++j)
                    acc[s][j] = __builtin_amdgcn_mfma_f32_16x16x32_bf16(
                        af[s], bf[j], acc[s][j], 0, 0, 0);
                accl[s] = __builtin_amdgcn_mfma_f32_16x16x32_bf16(
                    af[s], ones, accl[s], 0, 0, 0);
            }
            __builtin_amdgcn_s_setprio(0);
        }

        if (more) {                          // column factors for t+1
            float ee = ern - M2;
            float xin = hiE ? 0.2f * ee : ee;
            ldsE[nxt][hiE][colE] = exp2_fast(xin);
        }
        __syncthreads();                     // one barrier/tile: drains DMA+LDS
    }

    // epilogue: denominators + partial writes per row-set
#pragma unroll
    for (int s = 0; s < SETS; ++s) {
        float ls[4];
#pragma unroll
        for (int r = 0; r < 4; ++r) ls[r] = __shfl(accl[s][r], lane & 48, 64);

        float* ap = accP + ((size_t)ks * 4096 + nb + s * 64 + q * 4) * HO + h * 64 + c;
#pragma unroll
        for (int r = 0; r < 4; ++r)
#pragma unroll
            for (int j = 0; j < 4; ++j)
                ap[(size_t)r * HO + j * 16] = acc[s][j][r];
        if (c == 0) {
#pragma unroll
            for (int r = 0; r < 4; ++r)
                lP[((size_t)ks * H + h) * 4096 + nb + s * 64 + q * 4 + r] = ls[r];
        }
    }
}

// ---------------------------------------------------------------------------
// Phase C: combine key-split partials, divide, optional ELU.
// ---------------------------------------------------------------------------
static __device__ __forceinline__ void do_comb(
    int blk, int tid,
    const float* __restrict__ accP, const float* __restrict__ lP,
    unsigned short* __restrict__ outb, float* __restrict__ outf,
    int KS, int H, int lgHO, int do_elu)
{
    const int HO = 1 << lgHO;
    const int nvb = (4096 * HO) >> 8;        // virtual 256-thread work blocks
    for (int v = blk; v < nvb; v += 512) {
        const int idx = v * 256 + tid;
        const int n = idx >> lgHO, col = idx & (HO - 1), h = col >> 6;
        float s = 0.f, l = 0.f;
        for (int ks = 0; ks < KS; ++ks) {
            s += accP[((size_t)ks * 4096 + n) * HO + col];
            l += lP[((size_t)ks * H + h) * 4096 + n];
        }
        float vv = s / l;
        if (do_elu && vv < 0.f) vv = exp2_fast(vv * LOG2E) - 1.f;
        if (outf) outf[idx] = vv;
        else      outb[idx] = bf16_rne(vv);
    }
}

// ---------------------------------------------------------------------------
// The whole 3-layer GAT as ONE plain-launch persistent kernel: 9 software
// grid barriers replace 10 serialized dispatch boundaries.
// ---------------------------------------------------------------------------
__global__ __launch_bounds__(256, 2) void gat_all(
    const float* __restrict__ xf, const int* __restrict__ adj,
    const float* __restrict__ W0, const float* __restrict__ a0,
    const float* __restrict__ W1, const float* __restrict__ a1,
    const float* __restrict__ W2, const float* __restrict__ a2,
    float* __restrict__ out,
    unsigned long long* __restrict__ bits,
    unsigned short* __restrict__ hT, unsigned short* __restrict__ X12,
    unsigned short* __restrict__ Xc,
    unsigned short* __restrict__ W0t, unsigned short* __restrict__ W1t,
    unsigned short* __restrict__ W2t,
    float* __restrict__ el2, float* __restrict__ er2,
    unsigned* __restrict__ MxU,
    float* __restrict__ accP, float* __restrict__ lP,
    unsigned* __restrict__ gcnt)
{
    __shared__ unsigned short ldsH[2][64 * 128];   // 32 KB (att staging)
    __shared__ float ldsE[2][2][128];              // 2 KB  (att col factors)
    const int blk = blockIdx.x, tid = threadIdx.x;

    do_prep(blk, tid, xf, adj, W0, W1, W2, Xc, bits, W0t, W1t, W2t, MxU);
    grid_sync(gcnt + 0);

    // layer 0: K=128, H=4
    do_gemm(blk, tid, 4, Xc, 128, W0t, a0, hT, el2, er2, MxU + 0);
    grid_sync(gcnt + 1);
    do_att<2>(blk & 31, (blk >> 5) & 3, blk >> 7, tid, ldsH, ldsE,
              hT, el2, er2, MxU + 0, bits, accP, lP, 4, 1024, 256);
    grid_sync(gcnt + 2);
    do_comb(blk, tid, accP, lP, X12, nullptr, 4, 4, 8, 1);
    grid_sync(gcnt + 3);

    // layer 1: K=256, H=4
    do_gemm(blk, tid, 4, X12, 256, W1t, a1, hT, el2, er2, MxU + 4);
    grid_sync(gcnt + 4);
    do_att<2>(blk & 31, (blk >> 5) & 3, blk >> 7, tid, ldsH, ldsE,
              hT, el2, er2, MxU + 4, bits, accP, lP, 4, 1024, 256);
    grid_sync(gcnt + 5);
    do_comb(blk, tid, accP, lP, X12, nullptr, 4, 4, 8, 1);
    grid_sync(gcnt + 6);

    // layer 2: K=256, H=1, output f32 (no ELU)
    do_gemm(blk, tid, 1, X12, 256, W2t, a2, hT, el2, er2, MxU + 8);
    grid_sync(gcnt + 7);
    do_att<1>(blk & 63, 0, blk >> 6, tid, ldsH, ldsE,
              hT, el2, er2, MxU + 8, bits, accP, lP, 1, 512, 64);
    grid_sync(gcnt + 8);
    do_comb(blk, tid, accP, lP, nullptr, out, 8, 1, 6, 0);
}

// ---------------------------------------------------------------------------
extern "C" void kernel_launch(void* const* d_in, const int* in_sizes, int n_in,
                              void* d_out, int out_size, void* d_ws, size_t ws_size,
                              hipStream_t stream)
{
    (void)in_sizes; (void)n_in; (void)out_size; (void)ws_size;
    const float* x   = (const float*)d_in[0];
    const int*   adj = (const int*)d_in[1];
    const float* W0  = (const float*)d_in[2];
    const float* a0  = (const float*)d_in[3];
    const float* W1  = (const float*)d_in[4];
    const float* a1  = (const float*)d_in[5];
    const float* W2  = (const float*)d_in[6];
    const float* a2  = (const float*)d_in[7];

    char* p = (char*)d_ws;                                   // ~25 MB used
    unsigned long long* bits = (unsigned long long*)(p + 0x000000);  // 2 MB
    unsigned short* hT  = (unsigned short*)(p + 0x200000);           // 2 MB
    unsigned short* X12 = (unsigned short*)(p + 0x400000);           // 2 MB
    unsigned short* Xc  = (unsigned short*)(p + 0x600000);           // 1 MB
    unsigned short* W0t = (unsigned short*)(p + 0x700000);           // 64 KB
    unsigned short* W1t = (unsigned short*)(p + 0x710000);           // 128 KB
    unsigned short* W2t = (unsigned short*)(p + 0x730000);           // 32 KB
    float*    el2  = (float*)(p + 0x738000);                         // 64 KB
    float*    er2  = (float*)(p + 0x748000);                         // 64 KB
    unsigned* MxU  = (unsigned*)(p + 0x758000);                      // 48 B
    float*    accP = (float*)(p + 0x760000);                         // 16 MB
    float*    lP   = (float*)(p + 0x1760000);                        // 256 KB
    unsigned* gcnt = (unsigned*)(p + 0x17A0000);                     // 64 B

    // zero the 9 barrier counters (graph-capturable, part of each replay)
    hipMemsetAsync(gcnt, 0, 16 * sizeof(unsigned), stream);

    gat_all<<<GRID_BLOCKS, 256, 0, stream>>>(
        x, adj, W0, a0, W1, a1, W2, a2, (float*)d_out,
        bits, hT, X12, Xc, W0t, W1t, W2t, el2, er2, MxU, accP, lP, gcnt);
}

// Round 7
// 528.989 us; speedup vs baseline: 1.8698x; 1.8698x over previous
//
#include <hip/hip_runtime.h>

#define LOG2E 1.4426950408889634f

typedef float  f32x4 __attribute__((ext_vector_type(4)));
typedef float  f32x2 __attribute__((ext_vector_type(2)));
typedef int    i32x4 __attribute__((ext_vector_type(4)));
typedef short  s16x8 __attribute__((ext_vector_type(8)));
typedef unsigned long long u64x2 __attribute__((ext_vector_type(2)));

static __device__ __forceinline__ float exp2_fast(float x) {
#if __has_builtin(__builtin_amdgcn_exp2f)
    return __builtin_amdgcn_exp2f(x);
#else
    return exp2f(x);
#endif
}
static __device__ __forceinline__ unsigned short bf16_rne(float f) {
    unsigned u = __float_as_uint(f);
    u += 0x7FFFu + ((u >> 16) & 1u);
    return (unsigned short)(u >> 16);
}
// 1-bit signed bitfield extract -> 0 or 0xFFFFFFFF
static __device__ __forceinline__ int sbfe1(unsigned w, int pos) {
#if __has_builtin(__builtin_amdgcn_sbfe)
    return __builtin_amdgcn_sbfe((int)w, pos, 1);
#else
    return (int)(w << (31 - pos)) >> 31;
#endif
}
// pack hi16(u0) | hi16(u1)<<16 in one v_perm
static __device__ __forceinline__ unsigned pack_hi16(unsigned u1, unsigned u0) {
#if __has_builtin(__builtin_amdgcn_perm)
    return __builtin_amdgcn_perm(u1, u0, 0x07060302u);
#else
    return (u0 >> 16) | (u1 & 0xFFFF0000u);
#endif
}

#define GRID_BLOCKS 512u

// ---------------------------------------------------------------------------
// Software grid barrier, CDNA4-tuned.
// Round-6 lesson: ACQUIRE atomic loads in the spin emit a buffer_inv L2-walk
// PER POLL, and per-thread __threadfence() emits wbl2+inv per THREAD ->
// ~90 us/barrier. Fix: relaxed spin (sc1 load reads the coherence point, no
// walk) + exactly ONE release fence (wbl2) before arrival and ONE acquire
// fence (inv) after exit, tid0 only. All waves of a block share the CU L1 /
// XCD L2, so tid0's fences + __syncthreads cover the block.
// Monotonic counters, zeroed by captured hipMemsetAsync each replay.
// Residency of all 512 blocks guaranteed by __launch_bounds__(256,2).
// ---------------------------------------------------------------------------
static __device__ __forceinline__ void grid_sync(unsigned* cnt) {
    __syncthreads();
    if (threadIdx.x == 0) {
        __builtin_amdgcn_fence(__ATOMIC_RELEASE, "agent");   // waitcnt + wbl2 (once/block)
        __hip_atomic_fetch_add(cnt, 1u, __ATOMIC_RELAXED, __HIP_MEMORY_SCOPE_AGENT);
        while (__hip_atomic_load(cnt, __ATOMIC_RELAXED,
                                 __HIP_MEMORY_SCOPE_AGENT) < GRID_BLOCKS)
            __builtin_amdgcn_s_sleep(8);
        __builtin_amdgcn_fence(__ATOMIC_ACQUIRE, "agent");   // buffer_inv (once/block)
    }
    __syncthreads();
}

// ---------------------------------------------------------------------------
// Phase 0: adj -> bitmask, x -> bf16, W -> bf16 transposed, Mx init.
// ---------------------------------------------------------------------------
static __device__ __forceinline__ void do_prep(
    int blk, int tid,
    const float* __restrict__ xf, const int* __restrict__ adj,
    const float* __restrict__ W0, const float* __restrict__ W1,
    const float* __restrict__ W2,
    unsigned short* __restrict__ xc, unsigned long long* __restrict__ bits,
    unsigned short* __restrict__ W0t, unsigned short* __restrict__ W1t,
    unsigned short* __restrict__ W2t, unsigned* __restrict__ MxU)
{
    const int w = tid >> 6, lane = tid & 63;
    for (int b = blk; b < 16384; b += 512) {     // adj -> bits, 1024 elem/unit
        const int base = b * 1024 + w * 256;
        unsigned long long m[4];
#pragma unroll
        for (int r = 0; r < 4; ++r)
            m[r] = __ballot(adj[base + r * 64 + lane] != 0);
        if (lane == 0) {
            u64x2 lo = {m[0], m[1]}, hi = {m[2], m[3]};
            *(u64x2*)(bits + (base >> 6))     = lo;
            *(u64x2*)(bits + (base >> 6) + 2) = hi;
        }
    }
    for (int b = blk; b < 2048; b += 512) {      // x f32 -> bf16
        int i = b * 256 + tid;
        xc[i] = bf16_rne(xf[i]);
    }
    if (blk < 449) {                             // W transpose + Mx init
        int gid = blk * 256 + tid;
        if (gid < 32768) {                       // W0: (4,128,64)
            int h = gid >> 13, d = (gid >> 6) & 127, o = gid & 63;
            W0t[(h * 64 + o) * 128 + d] = bf16_rne(W0[gid]);
        } else if (gid < 98304) {                // W1: (4,256,64)
            int g = gid - 32768;
            int h = g >> 14, d = (g >> 6) & 255, o = g & 63;
            W1t[(h * 64 + o) * 256 + d] = bf16_rne(W1[g]);
        } else if (gid < 114688) {               // W2: (1,256,64)
            int g = gid - 98304;
            int d = g >> 6, o = g & 63;
            W2t[o * 256 + d] = bf16_rne(W2[g]);
        } else if (gid < 114700) {               // Mx[12] = encoded -inf
            MxU[gid - 114688] = 0x007FFFFFu;
        }
    }
}

// ---------------------------------------------------------------------------
// Phase G: h = X @ W (MFMA 16x16x32 bf16) -> hT[h][o][n] (bf16),
// fused el2/er2 and per-head max of er2 via encoded atomicMax.
// 64 rows per block (4 waves x 16). Active blocks: 64*H.
// ---------------------------------------------------------------------------
static __device__ __forceinline__ void do_gemm(
    int blk, int tid, int H,
    const unsigned short* __restrict__ X, int K,
    const unsigned short* __restrict__ Wt, const float* __restrict__ a,
    unsigned short* __restrict__ hT,
    float* __restrict__ el2, float* __restrict__ er2,
    unsigned* __restrict__ MxU)
{
    if (blk >= 64 * H) return;
    const int h = blk >> 6, bx = blk & 63;
    const int lane = tid & 63, w = tid >> 6;
    const int c = lane & 15, q = lane >> 4;
    const int nb = bx * 64 + w * 16;
    const unsigned short* xrow = X + (size_t)(nb + c) * K + q * 8;
    const unsigned short* wb   = Wt + ((size_t)h * 64 + c) * K + q * 8;

    f32x4 acc[4] = {{0,0,0,0},{0,0,0,0},{0,0,0,0},{0,0,0,0}};
    for (int kk = 0; kk < K; kk += 32) {
        s16x8 af = *(const s16x8*)(xrow + kk);
#pragma unroll
        for (int j = 0; j < 4; ++j) {
            s16x8 bf = *(const s16x8*)(wb + (size_t)(j * 16) * K + kk);
            acc[j] = __builtin_amdgcn_mfma_f32_16x16x32_bf16(af, bf, acc[j], 0, 0, 0);
        }
    }
    // C/D layout: col = lane&15, row = q*4 + reg  ->  hT[h][o][n]
#pragma unroll
    for (int j = 0; j < 4; ++j) {
        unsigned d0 = (unsigned)bf16_rne(acc[j][0]) | ((unsigned)bf16_rne(acc[j][1]) << 16);
        unsigned d1 = (unsigned)bf16_rne(acc[j][2]) | ((unsigned)bf16_rne(acc[j][3]) << 16);
        unsigned short* dst = hT + ((size_t)h * 64 + j * 16 + c) * 4096 + nb + q * 4;
        ((unsigned*)dst)[0] = d0;
        ((unsigned*)dst)[1] = d1;
    }
    const float* ab = a + h * 128;
    float elr[4] = {0,0,0,0}, err[4] = {0,0,0,0};
#pragma unroll
    for (int j = 0; j < 4; ++j) {
        float al = ab[j * 16 + c];
        float ar = ab[64 + j * 16 + c];
#pragma unroll
        for (int r = 0; r < 4; ++r) {
            elr[r] = fmaf(al, acc[j][r], elr[r]);
            err[r] = fmaf(ar, acc[j][r], err[r]);
        }
    }
#pragma unroll
    for (int m = 1; m <= 8; m <<= 1) {
#pragma unroll
        for (int r = 0; r < 4; ++r) {
            elr[r] += __shfl_xor(elr[r], m, 64);
            err[r] += __shfl_xor(err[r], m, 64);
        }
    }
    if (c == 0) {
#pragma unroll
        for (int r = 0; r < 4; ++r) {
            int n = nb + q * 4 + r;
            el2[h * 4096 + n] = elr[r] * LOG2E;
            er2[h * 4096 + n] = err[r] * LOG2E;
        }
    }
    float mm = fmaxf(fmaxf(err[0], err[1]), fmaxf(err[2], err[3]));
    mm = fmaxf(mm, __shfl_xor(mm, 16, 64));
    mm = fmaxf(mm, __shfl_xor(mm, 32, 64));
    if (lane == 0) {
        unsigned u = __float_as_uint(mm * LOG2E);
        unsigned key = (u & 0x80000000u) ? ~u : (u | 0x80000000u);
        atomicMax(MxU + h, key);
    }
}

// ---------------------------------------------------------------------------
// Phase A: fused masked-softmax attention, factorized exp2.
//   p[n][m] = max(Al[n]*Ar[m], Bl[n]*Br[m]) & adjbit      (p <= 1)
// SETS row-sets of 64 q-rows share each staged 64x128 key tile. Double-
// buffered global_load_lds staging (pre-swizzled source), one barrier/tile.
// ---------------------------------------------------------------------------
template <int SETS>
static __device__ __forceinline__ void do_att(
    int bx, int h, int ks, int tid,
    unsigned short (&ldsH)[2][64 * 128], float (&ldsE)[2][2][128],
    const unsigned short* __restrict__ hT,
    const float* __restrict__ el2g, const float* __restrict__ er2g,
    const unsigned* __restrict__ MxU,
    const unsigned long long* __restrict__ bits,
    float* __restrict__ accP, float* __restrict__ lP,
    int H, int KPS, int HO)
{
    const int lane = tid & 63, w = tid >> 6;
    const int c = lane & 15, q = lane >> 4, q8 = q * 8;
    const int nb = bx * (64 * SETS) + w * 16;

    unsigned kM = MxU[h];
    float M2 = __uint_as_float((kM & 0x80000000u) ? (kM & 0x7FFFFFFFu) : ~kM);

    f32x2 Av[SETS], Bv[SETS];
    const char* bitrow[SETS];
#pragma unroll
    for (int s = 0; s < SETS; ++s) {
        int rowA = nb + s * 64 + c;
        float e2 = el2g[h * 4096 + rowA];
        float xx = e2 + M2;
        float C2 = fmaxf(xx, 0.2f * xx);     // C2 >= all scores of this row
        float Al = exp2_fast(xx - C2);
        float Bl = exp2_fast(fmaf(0.2f, xx, -C2));
        Av[s] = (f32x2){Al, Al};
        Bv[s] = (f32x2){Bl, Bl};
        bitrow[s] = (const char*)bits + (size_t)rowA * 512 + (size_t)(KPS >> 3) * ks;
    }

    const unsigned short* hTh = hT + (size_t)h * 64 * 4096;
    const float* erh = er2g + h * 4096;
    const int tiles = KPS >> 7;
    const int kbase = ks * KPS;
    const int colE = tid & 127, hiE = tid >> 7;  // ldsE fill: 1 exp2/thread

    // DMA stage: LDS dest linear in lane; swizzle applied on the GLOBAL src
    // address (m173). Tile = 64 rows x 16 groups of 16B; group g at g^(o&7).
    auto STAGE = [&](int buf, int mabs_) {
#pragma unroll
        for (int i = 0; i < 4; ++i) {
            int cidx = i * 256 + tid;
            int o = cidx >> 4, g = cidx & 15;
            const unsigned short* sp =
                hTh + (size_t)o * 4096 + mabs_ + ((g ^ (o & 7)) << 3);
            unsigned short* dp = &ldsH[buf][(i * 256 + (tid & ~63)) << 3];
            __builtin_amdgcn_global_load_lds(
                (const __attribute__((address_space(1))) void*)sp,
                (__attribute__((address_space(3))) void*)dp, 16, 0, 0);
        }
    };

    s16x8 ones = {0,0,0,0,0,0,0,0};
    if (c == 0) {
#pragma unroll
        for (int i = 0; i < 8; ++i) ones[i] = (short)0x3F80;   // bf16 1.0, col 0
    }
    f32x4 acc[SETS][4];
    f32x4 accl[SETS];
#pragma unroll
    for (int s = 0; s < SETS; ++s) {
        accl[s] = (f32x4){0,0,0,0};
#pragma unroll
        for (int j = 0; j < 4; ++j) acc[s][j] = (f32x4){0,0,0,0};
    }

    // ---- prologue: stage tile 0 (DMA + column factors + bits) ----
    STAGE(0, kbase);
    {
        float ee = erh[kbase + colE] - M2;
        float xin = hiE ? 0.2f * ee : ee;
        ldsE[0][hiE][colE] = exp2_fast(xin);
    }
    i32x4 bA[SETS];
#pragma unroll
    for (int s = 0; s < SETS; ++s) bA[s] = *(const i32x4*)(bitrow[s]);
    __syncthreads();                         // drains DMA (vmcnt 0)

    for (int t = 0; t < tiles; ++t) {
        const int cur = t & 1, nxt = cur ^ 1;
        const bool more = (t + 1 < tiles);
        const unsigned short* Hc = ldsH[cur];
        const float* EcA = ldsE[cur][0];
        const float* EcB = ldsE[cur][1];

        float ern = 0.f;
        if (more) {
            const int mn = kbase + (t + 1) * 128;
            STAGE(nxt, mn);                  // async, drains at the barrier
            ern = erh[mn + colE];
        }
        int bw[SETS][4];
#pragma unroll
        for (int s = 0; s < SETS; ++s) {
            bw[s][0] = bA[s][0]; bw[s][1] = bA[s][1];
            bw[s][2] = bA[s][2]; bw[s][3] = bA[s][3];
        }
        if (more) {
#pragma unroll
            for (int s = 0; s < SETS; ++s)
                bA[s] = *(const i32x4*)(bitrow[s] + (t + 1) * 16);
        }

#pragma unroll
        for (int cc = 0; cc < 4; ++cc) {
            const int kl = cc * 32 + q8;
            const f32x4* eap = (const f32x4*)(EcA + kl);
            const f32x4* ebp = (const f32x4*)(EcB + kl);
            f32x4 eA0 = eap[0], eA1 = eap[1];      // Ar for 8 cols
            f32x4 eB0 = ebp[0], eB1 = ebp[1];      // Br for 8 cols
            const int klx = kl ^ ((c & 7) << 3);
            const unsigned short* lb = Hc + c * 128 + klx;
            s16x8 bf[4];
#pragma unroll
            for (int j = 0; j < 4; ++j)
                bf[j] = *(const s16x8*)(lb + (size_t)(j * 16) * 128);

            s16x8 af[SETS];
#pragma unroll
            for (int s = 0; s < SETS; ++s) {
                const unsigned word = (unsigned)bw[s][cc];
                unsigned pd[4];
#pragma unroll
                for (int jj = 0; jj < 4; ++jj) {
                    f32x2 ea = (jj == 0) ? eA0.xy : (jj == 1) ? eA0.zw
                             : (jj == 2) ? eA1.xy : eA1.zw;
                    f32x2 eb = (jj == 0) ? eB0.xy : (jj == 1) ? eB0.zw
                             : (jj == 2) ? eB1.xy : eB1.zw;
                    f32x2 pa = Av[s] * ea;         // v_pk_mul_f32
                    f32x2 pb = Bv[s] * eb;         // v_pk_mul_f32
                    float p0 = fmaxf(pa.x, pb.x);
                    float p1 = fmaxf(pa.y, pb.y);
                    unsigned u0 = __float_as_uint(p0) & (unsigned)sbfe1(word, q8 + 2 * jj);
                    unsigned u1 = __float_as_uint(p1) & (unsigned)sbfe1(word, q8 + 2 * jj + 1);
                    pd[jj] = pack_hi16(u1, u0);    // truncate-pack 2 bf16
                }
                union { unsigned u[4]; s16x8 s8; } afu;
                afu.u[0] = pd[0]; afu.u[1] = pd[1];
                afu.u[2] = pd[2]; afu.u[3] = pd[3];
                af[s] = afu.s8;
            }
            __builtin_amdgcn_s_setprio(1);
#pragma unroll
            for (int s = 0; s < SETS; ++s) {
#pragma unroll
                for (int j = 0; j < 4; ++j)
                    acc[s][j] = __builtin_amdgcn_mfma_f32_16x16x32_bf16(
                        af[s], bf[j], acc[s][j], 0, 0, 0);
                accl[s] = __builtin_amdgcn_mfma_f32_16x16x32_bf16(
                    af[s], ones, accl[s], 0, 0, 0);
            }
            __builtin_amdgcn_s_setprio(0);
        }

        if (more) {                          // column factors for t+1
            float ee = ern - M2;
            float xin = hiE ? 0.2f * ee : ee;
            ldsE[nxt][hiE][colE] = exp2_fast(xin);
        }
        __syncthreads();                     // one barrier/tile: drains DMA+LDS
    }

    // epilogue: denominators + partial writes per row-set
#pragma unroll
    for (int s = 0; s < SETS; ++s) {
        float ls[4];
#pragma unroll
        for (int r = 0; r < 4; ++r) ls[r] = __shfl(accl[s][r], lane & 48, 64);

        float* ap = accP + ((size_t)ks * 4096 + nb + s * 64 + q * 4) * HO + h * 64 + c;
#pragma unroll
        for (int r = 0; r < 4; ++r)
#pragma unroll
            for (int j = 0; j < 4; ++j)
                ap[(size_t)r * HO + j * 16] = acc[s][j][r];
        if (c == 0) {
#pragma unroll
            for (int r = 0; r < 4; ++r)
                lP[((size_t)ks * H + h) * 4096 + nb + s * 64 + q * 4 + r] = ls[r];
        }
    }
}

// ---------------------------------------------------------------------------
// Phase C: combine key-split partials, divide, optional ELU.
// ---------------------------------------------------------------------------
static __device__ __forceinline__ void do_comb(
    int blk, int tid,
    const float* __restrict__ accP, const float* __restrict__ lP,
    unsigned short* __restrict__ outb, float* __restrict__ outf,
    int KS, int H, int lgHO, int do_elu)
{
    const int HO = 1 << lgHO;
    const int nvb = (4096 * HO) >> 8;        // virtual 256-thread work blocks
    for (int v = blk; v < nvb; v += 512) {
        const int idx = v * 256 + tid;
        const int n = idx >> lgHO, col = idx & (HO - 1), h = col >> 6;
        float s = 0.f, l = 0.f;
        for (int ks = 0; ks < KS; ++ks) {
            s += accP[((size_t)ks * 4096 + n) * HO + col];
            l += lP[((size_t)ks * H + h) * 4096 + n];
        }
        float vv = s / l;
        if (do_elu && vv < 0.f) vv = exp2_fast(vv * LOG2E) - 1.f;
        if (outf) outf[idx] = vv;
        else      outb[idx] = bf16_rne(vv);
    }
}

// ---------------------------------------------------------------------------
// The whole 3-layer GAT as ONE plain-launch persistent kernel: 9 software
// grid barriers replace 10 serialized dispatch boundaries.
// ---------------------------------------------------------------------------
__global__ __launch_bounds__(256, 2) void gat_all(
    const float* __restrict__ xf, const int* __restrict__ adj,
    const float* __restrict__ W0, const float* __restrict__ a0,
    const float* __restrict__ W1, const float* __restrict__ a1,
    const float* __restrict__ W2, const float* __restrict__ a2,
    float* __restrict__ out,
    unsigned long long* __restrict__ bits,
    unsigned short* __restrict__ hT, unsigned short* __restrict__ X12,
    unsigned short* __restrict__ Xc,
    unsigned short* __restrict__ W0t, unsigned short* __restrict__ W1t,
    unsigned short* __restrict__ W2t,
    float* __restrict__ el2, float* __restrict__ er2,
    unsigned* __restrict__ MxU,
    float* __restrict__ accP, float* __restrict__ lP,
    unsigned* __restrict__ gcnt)
{
    __shared__ unsigned short ldsH[2][64 * 128];   // 32 KB (att staging)
    __shared__ float ldsE[2][2][128];              // 2 KB  (att col factors)
    const int blk = blockIdx.x, tid = threadIdx.x;

    do_prep(blk, tid, xf, adj, W0, W1, W2, Xc, bits, W0t, W1t, W2t, MxU);
    grid_sync(gcnt + 0);

    // layer 0: K=128, H=4
    do_gemm(blk, tid, 4, Xc, 128, W0t, a0, hT, el2, er2, MxU + 0);
    grid_sync(gcnt + 1);
    do_att<2>(blk & 31, (blk >> 5) & 3, blk >> 7, tid, ldsH, ldsE,
              hT, el2, er2, MxU + 0, bits, accP, lP, 4, 1024, 256);
    grid_sync(gcnt + 2);
    do_comb(blk, tid, accP, lP, X12, nullptr, 4, 4, 8, 1);
    grid_sync(gcnt + 3);

    // layer 1: K=256, H=4
    do_gemm(blk, tid, 4, X12, 256, W1t, a1, hT, el2, er2, MxU + 4);
    grid_sync(gcnt + 4);
    do_att<2>(blk & 31, (blk >> 5) & 3, blk >> 7, tid, ldsH, ldsE,
              hT, el2, er2, MxU + 4, bits, accP, lP, 4, 1024, 256);
    grid_sync(gcnt + 5);
    do_comb(blk, tid, accP, lP, X12, nullptr, 4, 4, 8, 1);
    grid_sync(gcnt + 6);

    // layer 2: K=256, H=1, output f32 (no ELU)
    do_gemm(blk, tid, 1, X12, 256, W2t, a2, hT, el2, er2, MxU + 8);
    grid_sync(gcnt + 7);
    do_att<1>(blk & 63, 0, blk >> 6, tid, ldsH, ldsE,
              hT, el2, er2, MxU + 8, bits, accP, lP, 1, 512, 64);
    grid_sync(gcnt + 8);
    do_comb(blk, tid, accP, lP, nullptr, out, 8, 1, 6, 0);
}

// ---------------------------------------------------------------------------
extern "C" void kernel_launch(void* const* d_in, const int* in_sizes, int n_in,
                              void* d_out, int out_size, void* d_ws, size_t ws_size,
                              hipStream_t stream)
{
    (void)in_sizes; (void)n_in; (void)out_size; (void)ws_size;
    const float* x   = (const float*)d_in[0];
    const int*   adj = (const int*)d_in[1];
    const float* W0  = (const float*)d_in[2];
    const float* a0  = (const float*)d_in[3];
    const float* W1  = (const float*)d_in[4];
    const float* a1  = (const float*)d_in[5];
    const float* W2  = (const float*)d_in[6];
    const float* a2  = (const float*)d_in[7];

    char* p = (char*)d_ws;                                   // ~25 MB used
    unsigned long long* bits = (unsigned long long*)(p + 0x000000);  // 2 MB
    unsigned short* hT  = (unsigned short*)(p + 0x200000);           // 2 MB
    unsigned short* X12 = (unsigned short*)(p + 0x400000);           // 2 MB
    unsigned short* Xc  = (unsigned short*)(p + 0x600000);           // 1 MB
    unsigned short* W0t = (unsigned short*)(p + 0x700000);           // 64 KB
    unsigned short* W1t = (unsigned short*)(p + 0x710000);           // 128 KB
    unsigned short* W2t = (unsigned short*)(p + 0x730000);           // 32 KB
    float*    el2  = (float*)(p + 0x738000);                         // 64 KB
    float*    er2  = (float*)(p + 0x748000);                         // 64 KB
    unsigned* MxU  = (unsigned*)(p + 0x758000);                      // 48 B
    float*    accP = (float*)(p + 0x760000);                         // 16 MB
    float*    lP   = (float*)(p + 0x1760000);                        // 256 KB
    unsigned* gcnt = (unsigned*)(p + 0x17A0000);                     // 64 B

    // zero the 9 barrier counters (graph-capturable, part of each replay)
    hipMemsetAsync(gcnt, 0, 16 * sizeof(unsigned), stream);

    gat_all<<<GRID_BLOCKS, 256, 0, stream>>>(
        x, adj, W0, a0, W1, a1, W2, a2, (float*)d_out,
        bits, hT, X12, Xc, W0t, W1t, W2t, el2, er2, MxU, accP, lP, gcnt);
}

// Round 8
// 294.011 us; speedup vs baseline: 3.3642x; 1.7992x over previous
//
#include <hip/hip_runtime.h>

#define LOG2E 1.4426950408889634f

typedef float  f32x4 __attribute__((ext_vector_type(4)));
typedef float  f32x2 __attribute__((ext_vector_type(2)));
typedef int    i32x4 __attribute__((ext_vector_type(4)));
typedef short  s16x8 __attribute__((ext_vector_type(8)));
typedef unsigned long long u64x2 __attribute__((ext_vector_type(2)));

static __device__ __forceinline__ float exp2_fast(float x) {
#if __has_builtin(__builtin_amdgcn_exp2f)
    return __builtin_amdgcn_exp2f(x);
#else
    return exp2f(x);
#endif
}
static __device__ __forceinline__ unsigned short bf16_rne(float f) {
    unsigned u = __float_as_uint(f);
    u += 0x7FFFu + ((u >> 16) & 1u);
    return (unsigned short)(u >> 16);
}
// 1-bit signed bitfield extract -> 0 or 0xFFFFFFFF
static __device__ __forceinline__ int sbfe1(unsigned w, int pos) {
#if __has_builtin(__builtin_amdgcn_sbfe)
    return __builtin_amdgcn_sbfe((int)w, pos, 1);
#else
    return (int)(w << (31 - pos)) >> 31;
#endif
}
// pack hi16(u0) | hi16(u1)<<16 in one v_perm
static __device__ __forceinline__ unsigned pack_hi16(unsigned u1, unsigned u0) {
#if __has_builtin(__builtin_amdgcn_perm)
    return __builtin_amdgcn_perm(u1, u0, 0x07060302u);
#else
    return (u0 >> 16) | (u1 & 0xFFFF0000u);
#endif
}

#define GRID_BLOCKS 512u
#define RLX __ATOMIC_RELAXED
#define AGT __HIP_MEMORY_SCOPE_AGENT

// ---------------------------------------------------------------------------
// Hierarchical XCD-aware grid barrier.
// Round-7 lesson: per-BLOCK wbl2+inv walks serialize in each XCD's L2
// (~38 us/barrier for 64 pairs). Release only needs ONE wbl2 per XCD: the
// pre-barrier __syncthreads drains all waves' stores into the (write-through
// L1 ->) local L2, so the LAST arriver on each XCD flushes the shared L2 for
// everyone (wbl2 count 512 -> 8/barrier, and it overlaps other XCDs'
// arrivals). Acquire inv stays per-block (same-CU L1 may hold stale lines:
// blocks re-read the same hT addresses every layer) - proven in round 7.
// XCD self-id via s_getreg(HW_REG_XCC_ID) [HW-verified, learn_hip m09].
// Monotonic counters, zeroed by captured hipMemsetAsync each replay.
// Layout (uints): [0]=garr0 [8]=gdone0 [16+x*32]=xled0[x] [512+x*32]=xtot[x]
//                 [1024+b*512+x*32]=xarr_b[x] [1024+b*512+256]=gdone_b
// ---------------------------------------------------------------------------
struct BarCtx { unsigned myxcd, xtot, nact; };

static __device__ __forceinline__ unsigned read_xcc() {
    unsigned x;
    asm("s_getreg_b32 %0, hwreg(HW_REG_XCC_ID)" : "=s"(x));
    return x & 7u;
}
static __device__ __forceinline__ void bar_register(unsigned* g, BarCtx& bc) {
    bc.myxcd = read_xcc();
    __hip_atomic_fetch_add(g + 512 + bc.myxcd * 32, 1u, RLX, AGT);
}
// Barrier 0: flat arrival (xtot not final until all blocks entered), then
// leader election + single wbl2 per XCD. Caches xtot/nact for later barriers.
static __device__ __forceinline__ void bar_sync0(unsigned* g, BarCtx& bc) {
    __syncthreads();
    if (threadIdx.x == 0) {
        __builtin_amdgcn_fence(__ATOMIC_RELEASE, "workgroup");   // drain my VMEM
        __hip_atomic_fetch_add(g, 1u, RLX, AGT);
        while (__hip_atomic_load(g, RLX, AGT) < GRID_BLOCKS)
            __builtin_amdgcn_s_sleep(8);
        bc.xtot = __hip_atomic_load(g + 512 + bc.myxcd * 32, RLX, AGT);
        unsigned n = 0;
#pragma unroll
        for (int i = 0; i < 8; ++i)
            n += (__hip_atomic_load(g + 512 + i * 32, RLX, AGT) > 0) ? 1u : 0u;
        bc.nact = n;
        if (__hip_atomic_fetch_add(g + 16 + bc.myxcd * 32, 1u, RLX, AGT) == 0) {
            __builtin_amdgcn_fence(__ATOMIC_RELEASE, "agent");   // wbl2 (own XCD)
            __hip_atomic_fetch_add(g + 8, 1u, RLX, AGT);
        }
        while (__hip_atomic_load(g + 8, RLX, AGT) < bc.nact)
            __builtin_amdgcn_s_sleep(8);
        __builtin_amdgcn_fence(__ATOMIC_ACQUIRE, "agent");       // inv (per block)
    }
    __syncthreads();
}
// Barriers 1..8: per-XCD arrival; last arriver on the XCD is its leader
// (its XCD is quiescent -> safe to flush immediately, overlapping others).
static __device__ __forceinline__ void bar_sync(unsigned* g, int b, const BarCtx& bc) {
    __syncthreads();
    if (threadIdx.x == 0) {
        unsigned* base = g + 1024 + b * 512;
        __builtin_amdgcn_fence(__ATOMIC_RELEASE, "workgroup");   // drain my VMEM
        if (__hip_atomic_fetch_add(base + bc.myxcd * 32, 1u, RLX, AGT) == bc.xtot - 1u) {
            __builtin_amdgcn_fence(__ATOMIC_RELEASE, "agent");   // wbl2 (own XCD)
            __hip_atomic_fetch_add(base + 256, 1u, RLX, AGT);
        }
        while (__hip_atomic_load(base + 256, RLX, AGT) < bc.nact)
            __builtin_amdgcn_s_sleep(8);
        __builtin_amdgcn_fence(__ATOMIC_ACQUIRE, "agent");       // inv (per block)
    }
    __syncthreads();
}

// ---------------------------------------------------------------------------
// Phase 0: adj -> bitmask, x -> bf16, W -> bf16 transposed, Mx init.
// ---------------------------------------------------------------------------
static __device__ __forceinline__ void do_prep(
    int blk, int tid,
    const float* __restrict__ xf, const int* __restrict__ adj,
    const float* __restrict__ W0, const float* __restrict__ W1,
    const float* __restrict__ W2,
    unsigned short* __restrict__ xc, unsigned long long* __restrict__ bits,
    unsigned short* __restrict__ W0t, unsigned short* __restrict__ W1t,
    unsigned short* __restrict__ W2t, unsigned* __restrict__ MxU)
{
    const int w = tid >> 6, lane = tid & 63;
    for (int b = blk; b < 16384; b += 512) {     // adj -> bits, 1024 elem/unit
        const int base = b * 1024 + w * 256;
        unsigned long long m[4];
#pragma unroll
        for (int r = 0; r < 4; ++r)
            m[r] = __ballot(adj[base + r * 64 + lane] != 0);
        if (lane == 0) {
            u64x2 lo = {m[0], m[1]}, hi = {m[2], m[3]};
            *(u64x2*)(bits + (base >> 6))     = lo;
            *(u64x2*)(bits + (base >> 6) + 2) = hi;
        }
    }
    for (int b = blk; b < 2048; b += 512) {      // x f32 -> bf16
        int i = b * 256 + tid;
        xc[i] = bf16_rne(xf[i]);
    }
    if (blk < 449) {                             // W transpose + Mx init
        int gid = blk * 256 + tid;
        if (gid < 32768) {                       // W0: (4,128,64)
            int h = gid >> 13, d = (gid >> 6) & 127, o = gid & 63;
            W0t[(h * 64 + o) * 128 + d] = bf16_rne(W0[gid]);
        } else if (gid < 98304) {                // W1: (4,256,64)
            int g = gid - 32768;
            int h = g >> 14, d = (g >> 6) & 255, o = g & 63;
            W1t[(h * 64 + o) * 256 + d] = bf16_rne(W1[g]);
        } else if (gid < 114688) {               // W2: (1,256,64)
            int g = gid - 98304;
            int d = g >> 6, o = g & 63;
            W2t[o * 256 + d] = bf16_rne(W2[g]);
        } else if (gid < 114700) {               // Mx[12] = encoded -inf
            MxU[gid - 114688] = 0x007FFFFFu;
        }
    }
}

// ---------------------------------------------------------------------------
// Phase G: h = X @ W (MFMA 16x16x32 bf16) -> hT[h][o][n] (bf16),
// fused el2/er2 and per-head max of er2 via encoded atomicMax.
// 64 rows per block (4 waves x 16). Active blocks: 64*H.
// ---------------------------------------------------------------------------
static __device__ __forceinline__ void do_gemm(
    int blk, int tid, int H,
    const unsigned short* __restrict__ X, int K,
    const unsigned short* __restrict__ Wt, const float* __restrict__ a,
    unsigned short* __restrict__ hT,
    float* __restrict__ el2, float* __restrict__ er2,
    unsigned* __restrict__ MxU)
{
    if (blk >= 64 * H) return;
    const int h = blk >> 6, bx = blk & 63;
    const int lane = tid & 63, w = tid >> 6;
    const int c = lane & 15, q = lane >> 4;
    const int nb = bx * 64 + w * 16;
    const unsigned short* xrow = X + (size_t)(nb + c) * K + q * 8;
    const unsigned short* wb   = Wt + ((size_t)h * 64 + c) * K + q * 8;

    f32x4 acc[4] = {{0,0,0,0},{0,0,0,0},{0,0,0,0},{0,0,0,0}};
    for (int kk = 0; kk < K; kk += 32) {
        s16x8 af = *(const s16x8*)(xrow + kk);
#pragma unroll
        for (int j = 0; j < 4; ++j) {
            s16x8 bf = *(const s16x8*)(wb + (size_t)(j * 16) * K + kk);
            acc[j] = __builtin_amdgcn_mfma_f32_16x16x32_bf16(af, bf, acc[j], 0, 0, 0);
        }
    }
    // C/D layout: col = lane&15, row = q*4 + reg  ->  hT[h][o][n]
#pragma unroll
    for (int j = 0; j < 4; ++j) {
        unsigned d0 = (unsigned)bf16_rne(acc[j][0]) | ((unsigned)bf16_rne(acc[j][1]) << 16);
        unsigned d1 = (unsigned)bf16_rne(acc[j][2]) | ((unsigned)bf16_rne(acc[j][3]) << 16);
        unsigned short* dst = hT + ((size_t)h * 64 + j * 16 + c) * 4096 + nb + q * 4;
        ((unsigned*)dst)[0] = d0;
        ((unsigned*)dst)[1] = d1;
    }
    const float* ab = a + h * 128;
    float elr[4] = {0,0,0,0}, err[4] = {0,0,0,0};
#pragma unroll
    for (int j = 0; j < 4; ++j) {
        float al = ab[j * 16 + c];
        float ar = ab[64 + j * 16 + c];
#pragma unroll
        for (int r = 0; r < 4; ++r) {
            elr[r] = fmaf(al, acc[j][r], elr[r]);
            err[r] = fmaf(ar, acc[j][r], err[r]);
        }
    }
#pragma unroll
    for (int m = 1; m <= 8; m <<= 1) {
#pragma unroll
        for (int r = 0; r < 4; ++r) {
            elr[r] += __shfl_xor(elr[r], m, 64);
            err[r] += __shfl_xor(err[r], m, 64);
        }
    }
    if (c == 0) {
#pragma unroll
        for (int r = 0; r < 4; ++r) {
            int n = nb + q * 4 + r;
            el2[h * 4096 + n] = elr[r] * LOG2E;
            er2[h * 4096 + n] = err[r] * LOG2E;
        }
    }
    float mm = fmaxf(fmaxf(err[0], err[1]), fmaxf(err[2], err[3]));
    mm = fmaxf(mm, __shfl_xor(mm, 16, 64));
    mm = fmaxf(mm, __shfl_xor(mm, 32, 64));
    if (lane == 0) {
        unsigned u = __float_as_uint(mm * LOG2E);
        unsigned key = (u & 0x80000000u) ? ~u : (u | 0x80000000u);
        atomicMax(MxU + h, key);
    }
}

// ---------------------------------------------------------------------------
// Phase A: fused masked-softmax attention, factorized exp2.
//   p[n][m] = max(Al[n]*Ar[m], Bl[n]*Br[m]) & adjbit      (p <= 1)
// SETS row-sets of 64 q-rows share each staged 64x128 key tile. Double-
// buffered global_load_lds staging (pre-swizzled source), one barrier/tile.
// ---------------------------------------------------------------------------
template <int SETS>
static __device__ __forceinline__ void do_att(
    int bx, int h, int ks, int tid,
    unsigned short (&ldsH)[2][64 * 128], float (&ldsE)[2][2][128],
    const unsigned short* __restrict__ hT,
    const float* __restrict__ el2g, const float* __restrict__ er2g,
    const unsigned* __restrict__ MxU,
    const unsigned long long* __restrict__ bits,
    float* __restrict__ accP, float* __restrict__ lP,
    int H, int KPS, int HO)
{
    const int lane = tid & 63, w = tid >> 6;
    const int c = lane & 15, q = lane >> 4, q8 = q * 8;
    const int nb = bx * (64 * SETS) + w * 16;

    unsigned kM = MxU[h];
    float M2 = __uint_as_float((kM & 0x80000000u) ? (kM & 0x7FFFFFFFu) : ~kM);

    f32x2 Av[SETS], Bv[SETS];
    const char* bitrow[SETS];
#pragma unroll
    for (int s = 0; s < SETS; ++s) {
        int rowA = nb + s * 64 + c;
        float e2 = el2g[h * 4096 + rowA];
        float xx = e2 + M2;
        float C2 = fmaxf(xx, 0.2f * xx);     // C2 >= all scores of this row
        float Al = exp2_fast(xx - C2);
        float Bl = exp2_fast(fmaf(0.2f, xx, -C2));
        Av[s] = (f32x2){Al, Al};
        Bv[s] = (f32x2){Bl, Bl};
        bitrow[s] = (const char*)bits + (size_t)rowA * 512 + (size_t)(KPS >> 3) * ks;
    }

    const unsigned short* hTh = hT + (size_t)h * 64 * 4096;
    const float* erh = er2g + h * 4096;
    const int tiles = KPS >> 7;
    const int kbase = ks * KPS;
    const int colE = tid & 127, hiE = tid >> 7;  // ldsE fill: 1 exp2/thread

    // DMA stage: LDS dest linear in lane; swizzle applied on the GLOBAL src
    // address (m173). Tile = 64 rows x 16 groups of 16B; group g at g^(o&7).
    auto STAGE = [&](int buf, int mabs_) {
#pragma unroll
        for (int i = 0; i < 4; ++i) {
            int cidx = i * 256 + tid;
            int o = cidx >> 4, g = cidx & 15;
            const unsigned short* sp =
                hTh + (size_t)o * 4096 + mabs_ + ((g ^ (o & 7)) << 3);
            unsigned short* dp = &ldsH[buf][(i * 256 + (tid & ~63)) << 3];
            __builtin_amdgcn_global_load_lds(
                (const __attribute__((address_space(1))) void*)sp,
                (__attribute__((address_space(3))) void*)dp, 16, 0, 0);
        }
    };

    s16x8 ones = {0,0,0,0,0,0,0,0};
    if (c == 0) {
#pragma unroll
        for (int i = 0; i < 8; ++i) ones[i] = (short)0x3F80;   // bf16 1.0, col 0
    }
    f32x4 acc[SETS][4];
    f32x4 accl[SETS];
#pragma unroll
    for (int s = 0; s < SETS; ++s) {
        accl[s] = (f32x4){0,0,0,0};
#pragma unroll
        for (int j = 0; j < 4; ++j) acc[s][j] = (f32x4){0,0,0,0};
    }

    // ---- prologue: stage tile 0 (DMA + column factors + bits) ----
    STAGE(0, kbase);
    {
        float ee = erh[kbase + colE] - M2;
        float xin = hiE ? 0.2f * ee : ee;
        ldsE[0][hiE][colE] = exp2_fast(xin);
    }
    i32x4 bA[SETS];
#pragma unroll
    for (int s = 0; s < SETS; ++s) bA[s] = *(const i32x4*)(bitrow[s]);
    __syncthreads();                         // drains DMA (vmcnt 0)

    for (int t = 0; t < tiles; ++t) {
        const int cur = t & 1, nxt = cur ^ 1;
        const bool more = (t + 1 < tiles);
        const unsigned short* Hc = ldsH[cur];
        const float* EcA = ldsE[cur][0];
        const float* EcB = ldsE[cur][1];

        float ern = 0.f;
        if (more) {
            const int mn = kbase + (t + 1) * 128;
            STAGE(nxt, mn);                  // async, drains at the barrier
            ern = erh[mn + colE];
        }
        int bw[SETS][4];
#pragma unroll
        for (int s = 0; s < SETS; ++s) {
            bw[s][0] = bA[s][0]; bw[s][1] = bA[s][1];
            bw[s][2] = bA[s][2]; bw[s][3] = bA[s][3];
        }
        if (more) {
#pragma unroll
            for (int s = 0; s < SETS; ++s)
                bA[s] = *(const i32x4*)(bitrow[s] + (t + 1) * 16);
        }

#pragma unroll
        for (int cc = 0; cc < 4; ++cc) {
            const int kl = cc * 32 + q8;
            const f32x4* eap = (const f32x4*)(EcA + kl);
            const f32x4* ebp = (const f32x4*)(EcB + kl);
            f32x4 eA0 = eap[0], eA1 = eap[1];      // Ar for 8 cols
            f32x4 eB0 = ebp[0], eB1 = ebp[1];      // Br for 8 cols
            const int klx = kl ^ ((c & 7) << 3);
            const unsigned short* lb = Hc + c * 128 + klx;
            s16x8 bf[4];
#pragma unroll
            for (int j = 0; j < 4; ++j)
                bf[j] = *(const s16x8*)(lb + (size_t)(j * 16) * 128);

            s16x8 af[SETS];
#pragma unroll
            for (int s = 0; s < SETS; ++s) {
                const unsigned word = (unsigned)bw[s][cc];
                unsigned pd[4];
#pragma unroll
                for (int jj = 0; jj < 4; ++jj) {
                    f32x2 ea = (jj == 0) ? eA0.xy : (jj == 1) ? eA0.zw
                             : (jj == 2) ? eA1.xy : eA1.zw;
                    f32x2 eb = (jj == 0) ? eB0.xy : (jj == 1) ? eB0.zw
                             : (jj == 2) ? eB1.xy : eB1.zw;
                    f32x2 pa = Av[s] * ea;         // v_pk_mul_f32
                    f32x2 pb = Bv[s] * eb;         // v_pk_mul_f32
                    float p0 = fmaxf(pa.x, pb.x);
                    float p1 = fmaxf(pa.y, pb.y);
                    unsigned u0 = __float_as_uint(p0) & (unsigned)sbfe1(word, q8 + 2 * jj);
                    unsigned u1 = __float_as_uint(p1) & (unsigned)sbfe1(word, q8 + 2 * jj + 1);
                    pd[jj] = pack_hi16(u1, u0);    // truncate-pack 2 bf16
                }
                union { unsigned u[4]; s16x8 s8; } afu;
                afu.u[0] = pd[0]; afu.u[1] = pd[1];
                afu.u[2] = pd[2]; afu.u[3] = pd[3];
                af[s] = afu.s8;
            }
            __builtin_amdgcn_s_setprio(1);
#pragma unroll
            for (int s = 0; s < SETS; ++s) {
#pragma unroll
                for (int j = 0; j < 4; ++j)
                    acc[s][j] = __builtin_amdgcn_mfma_f32_16x16x32_bf16(
                        af[s], bf[j], acc[s][j], 0, 0, 0);
                accl[s] = __builtin_amdgcn_mfma_f32_16x16x32_bf16(
                    af[s], ones, accl[s], 0, 0, 0);
            }
            __builtin_amdgcn_s_setprio(0);
        }

        if (more) {                          // column factors for t+1
            float ee = ern - M2;
            float xin = hiE ? 0.2f * ee : ee;
            ldsE[nxt][hiE][colE] = exp2_fast(xin);
        }
        __syncthreads();                     // one barrier/tile: drains DMA+LDS
    }

    // epilogue: denominators + partial writes per row-set
#pragma unroll
    for (int s = 0; s < SETS; ++s) {
        float ls[4];
#pragma unroll
        for (int r = 0; r < 4; ++r) ls[r] = __shfl(accl[s][r], lane & 48, 64);

        float* ap = accP + ((size_t)ks * 4096 + nb + s * 64 + q * 4) * HO + h * 64 + c;
#pragma unroll
        for (int r = 0; r < 4; ++r)
#pragma unroll
            for (int j = 0; j < 4; ++j)
                ap[(size_t)r * HO + j * 16] = acc[s][j][r];
        if (c == 0) {
#pragma unroll
            for (int r = 0; r < 4; ++r)
                lP[((size_t)ks * H + h) * 4096 + nb + s * 64 + q * 4 + r] = ls[r];
        }
    }
}

// ---------------------------------------------------------------------------
// Phase C: combine key-split partials, divide, optional ELU.
// ---------------------------------------------------------------------------
static __device__ __forceinline__ void do_comb(
    int blk, int tid,
    const float* __restrict__ accP, const float* __restrict__ lP,
    unsigned short* __restrict__ outb, float* __restrict__ outf,
    int KS, int H, int lgHO, int do_elu)
{
    const int HO = 1 << lgHO;
    const int nvb = (4096 * HO) >> 8;        // virtual 256-thread work blocks
    for (int v = blk; v < nvb; v += 512) {
        const int idx = v * 256 + tid;
        const int n = idx >> lgHO, col = idx & (HO - 1), h = col >> 6;
        float s = 0.f, l = 0.f;
        for (int ks = 0; ks < KS; ++ks) {
            s += accP[((size_t)ks * 4096 + n) * HO + col];
            l += lP[((size_t)ks * H + h) * 4096 + n];
        }
        float vv = s / l;
        if (do_elu && vv < 0.f) vv = exp2_fast(vv * LOG2E) - 1.f;
        if (outf) outf[idx] = vv;
        else      outb[idx] = bf16_rne(vv);
    }
}

// ---------------------------------------------------------------------------
// The whole 3-layer GAT as ONE plain-launch persistent kernel: 9 software
// grid barriers (hierarchical, 1 wbl2/XCD) replace 10 dispatch boundaries.
// ---------------------------------------------------------------------------
__global__ __launch_bounds__(256, 2) void gat_all(
    const float* __restrict__ xf, const int* __restrict__ adj,
    const float* __restrict__ W0, const float* __restrict__ a0,
    const float* __restrict__ W1, const float* __restrict__ a1,
    const float* __restrict__ W2, const float* __restrict__ a2,
    float* __restrict__ out,
    unsigned long long* __restrict__ bits,
    unsigned short* __restrict__ hT, unsigned short* __restrict__ X12,
    unsigned short* __restrict__ Xc,
    unsigned short* __restrict__ W0t, unsigned short* __restrict__ W1t,
    unsigned short* __restrict__ W2t,
    float* __restrict__ el2, float* __restrict__ er2,
    unsigned* __restrict__ MxU,
    float* __restrict__ accP, float* __restrict__ lP,
    unsigned* __restrict__ gcnt)
{
    __shared__ unsigned short ldsH[2][64 * 128];   // 32 KB (att staging)
    __shared__ float ldsE[2][2][128];              // 2 KB  (att col factors)
    const int blk = blockIdx.x, tid = threadIdx.x;

    BarCtx bc;
    if (tid == 0) bar_register(gcnt, bc);          // xtot[myxcd]++ at entry

    do_prep(blk, tid, xf, adj, W0, W1, W2, Xc, bits, W0t, W1t, W2t, MxU);
    bar_sync0(gcnt, bc);

    // layer 0: K=128, H=4
    do_gemm(blk, tid, 4, Xc, 128, W0t, a0, hT, el2, er2, MxU + 0);
    bar_sync(gcnt, 1, bc);
    do_att<2>(blk & 31, (blk >> 5) & 3, blk >> 7, tid, ldsH, ldsE,
              hT, el2, er2, MxU + 0, bits, accP, lP, 4, 1024, 256);
    bar_sync(gcnt, 2, bc);
    do_comb(blk, tid, accP, lP, X12, nullptr, 4, 4, 8, 1);
    bar_sync(gcnt, 3, bc);

    // layer 1: K=256, H=4
    do_gemm(blk, tid, 4, X12, 256, W1t, a1, hT, el2, er2, MxU + 4);
    bar_sync(gcnt, 4, bc);
    do_att<2>(blk & 31, (blk >> 5) & 3, blk >> 7, tid, ldsH, ldsE,
              hT, el2, er2, MxU + 4, bits, accP, lP, 4, 1024, 256);
    bar_sync(gcnt, 5, bc);
    do_comb(blk, tid, accP, lP, X12, nullptr, 4, 4, 8, 1);
    bar_sync(gcnt, 6, bc);

    // layer 2: K=256, H=1, output f32 (no ELU)
    do_gemm(blk, tid, 1, X12, 256, W2t, a2, hT, el2, er2, MxU + 8);
    bar_sync(gcnt, 7, bc);
    do_att<1>(blk & 63, 0, blk >> 6, tid, ldsH, ldsE,
              hT, el2, er2, MxU + 8, bits, accP, lP, 1, 512, 64);
    bar_sync(gcnt, 8, bc);
    do_comb(blk, tid, accP, lP, nullptr, out, 8, 1, 6, 0);
}

// ---------------------------------------------------------------------------
extern "C" void kernel_launch(void* const* d_in, const int* in_sizes, int n_in,
                              void* d_out, int out_size, void* d_ws, size_t ws_size,
                              hipStream_t stream)
{
    (void)in_sizes; (void)n_in; (void)out_size; (void)ws_size;
    const float* x   = (const float*)d_in[0];
    const int*   adj = (const int*)d_in[1];
    const float* W0  = (const float*)d_in[2];
    const float* a0  = (const float*)d_in[3];
    const float* W1  = (const float*)d_in[4];
    const float* a1  = (const float*)d_in[5];
    const float* W2  = (const float*)d_in[6];
    const float* a2  = (const float*)d_in[7];

    char* p = (char*)d_ws;                                   // ~25 MB used
    unsigned long long* bits = (unsigned long long*)(p + 0x000000);  // 2 MB
    unsigned short* hT  = (unsigned short*)(p + 0x200000);           // 2 MB
    unsigned short* X12 = (unsigned short*)(p + 0x400000);           // 2 MB
    unsigned short* Xc  = (unsigned short*)(p + 0x600000);           // 1 MB
    unsigned short* W0t = (unsigned short*)(p + 0x700000);           // 64 KB
    unsigned short* W1t = (unsigned short*)(p + 0x710000);           // 128 KB
    unsigned short* W2t = (unsigned short*)(p + 0x730000);           // 32 KB
    float*    el2  = (float*)(p + 0x738000);                         // 64 KB
    float*    er2  = (float*)(p + 0x748000);                         // 64 KB
    unsigned* MxU  = (unsigned*)(p + 0x758000);                      // 48 B
    float*    accP = (float*)(p + 0x760000);                         // 16 MB
    float*    lP   = (float*)(p + 0x1760000);                        // 256 KB
    unsigned* gcnt = (unsigned*)(p + 0x17A0000);                     // 32 KB

    // zero barrier state (garr/gdone/xled/xtot/xarr), captured per replay
    hipMemsetAsync(gcnt, 0, 0x8000, stream);

    gat_all<<<GRID_BLOCKS, 256, 0, stream>>>(
        x, adj, W0, a0, W1, a1, W2, a2, (float*)d_out,
        bits, hT, X12, Xc, W0t, W1t, W2t, el2, er2, MxU, accP, lP, gcnt);
}

// Round 9
// 268.674 us; speedup vs baseline: 3.6814x; 1.0943x over previous
//
#include <hip/hip_runtime.h>

#define LOG2E 1.4426950408889634f

typedef float  f32x4 __attribute__((ext_vector_type(4)));
typedef float  f32x2 __attribute__((ext_vector_type(2)));
typedef int    i32x4 __attribute__((ext_vector_type(4)));
typedef short  s16x8 __attribute__((ext_vector_type(8)));
typedef unsigned long long u64x2 __attribute__((ext_vector_type(2)));

static __device__ __forceinline__ float exp2_fast(float x) {
#if __has_builtin(__builtin_amdgcn_exp2f)
    return __builtin_amdgcn_exp2f(x);
#else
    return exp2f(x);
#endif
}
static __device__ __forceinline__ unsigned short bf16_rne(float f) {
    unsigned u = __float_as_uint(f);
    u += 0x7FFFu + ((u >> 16) & 1u);
    return (unsigned short)(u >> 16);
}
// 1-bit signed bitfield extract -> 0 or 0xFFFFFFFF
static __device__ __forceinline__ int sbfe1(unsigned w, int pos) {
#if __has_builtin(__builtin_amdgcn_sbfe)
    return __builtin_amdgcn_sbfe((int)w, pos, 1);
#else
    return (int)(w << (31 - pos)) >> 31;
#endif
}
// pack hi16(u0) | hi16(u1)<<16 in one v_perm
static __device__ __forceinline__ unsigned pack_hi16(unsigned u1, unsigned u0) {
#if __has_builtin(__builtin_amdgcn_perm)
    return __builtin_amdgcn_perm(u1, u0, 0x07060302u);
#else
    return (u0 >> 16) | (u1 & 0xFFFF0000u);
#endif
}

#define GRID_BLOCKS 512u
#define RLX __ATOMIC_RELAXED
#define AGT __HIP_MEMORY_SCOPE_AGENT

// ---------------------------------------------------------------------------
// Hierarchical XCD-aware grid barrier, v3.
// Round-8 lesson (quantified): cache-op walks serialize in each XCD's L2 at
// ~0.33us each. Round 8 cut wbl2 512->8/barrier (saved 21us/barrier, exactly
// as modeled); the residual ~17us/barrier is the per-BLOCK acquire
// buffer_inv sc1 (L1+L2 walk) x 64/XCD. Only ONE L2 invalidate per XCD is
// needed; each block only needs its own CU L1 cleared. gfx950 SC bits select
// invalidate scope: bare `buffer_inv` = CU/L1 scope, no L2 walk.
// Protocol/barrier: last-arriver leader per XCD: wbl2 -> gdone++ -> spin
// gdone==nact -> fence(acquire,agent) [L2+L1 inv, once per XCD] -> set flag.
// Others: spin flag (relaxed, no walks) -> bare buffer_inv (L1 only).
// Stale lines cannot re-enter L2 after the leader's inv (nothing writes
// stale), so non-leaders' refills are clean.
// XCD self-id via s_getreg(HW_REG_XCC_ID) [HW-verified, learn_hip m09].
// Monotonic counters, zeroed by captured hipMemsetAsync each replay.
// ---------------------------------------------------------------------------
struct BarCtx { unsigned myxcd, xtot, nact; };

static __device__ __forceinline__ unsigned read_xcc() {
    unsigned x;
    asm("s_getreg_b32 %0, hwreg(HW_REG_XCC_ID)" : "=s"(x));
    return x & 7u;
}
static __device__ __forceinline__ void l1_inv() {
    asm volatile("buffer_inv\n\ts_waitcnt vmcnt(0)" ::: "memory");
}
static __device__ __forceinline__ void bar_register(unsigned* g, BarCtx& bc) {
    bc.myxcd = read_xcc();
    __hip_atomic_fetch_add(g + 512 + bc.myxcd * 32, 1u, RLX, AGT);
}
// Barrier 0: flat arrival (xtot not final until all blocks entered); then
// per-XCD first-arriver is leader. Caches xtot/nact for later barriers.
// Layout (uints): [0]=garr [8]=gdone [16+x*32]=xled [512+x*32]=xtot
//                 [768+x*8]=inv-flag
static __device__ __forceinline__ void bar_sync0(unsigned* g, BarCtx& bc) {
    __syncthreads();
    if (threadIdx.x == 0) {
        __builtin_amdgcn_fence(__ATOMIC_RELEASE, "workgroup");   // drain my VMEM
        __hip_atomic_fetch_add(g, 1u, RLX, AGT);
        while (__hip_atomic_load(g, RLX, AGT) < GRID_BLOCKS)
            __builtin_amdgcn_s_sleep(8);
        bc.xtot = __hip_atomic_load(g + 512 + bc.myxcd * 32, RLX, AGT);
        unsigned n = 0;
#pragma unroll
        for (int i = 0; i < 8; ++i)
            n += (__hip_atomic_load(g + 512 + i * 32, RLX, AGT) > 0) ? 1u : 0u;
        bc.nact = n;
        if (__hip_atomic_fetch_add(g + 16 + bc.myxcd * 32, 1u, RLX, AGT) == 0) {
            __builtin_amdgcn_fence(__ATOMIC_RELEASE, "agent");   // wbl2 (own XCD)
            __hip_atomic_fetch_add(g + 8, 1u, RLX, AGT);
            while (__hip_atomic_load(g + 8, RLX, AGT) < bc.nact)
                __builtin_amdgcn_s_sleep(8);
            __builtin_amdgcn_fence(__ATOMIC_ACQUIRE, "agent");   // L2 inv, once/XCD
            __hip_atomic_store(g + 768 + bc.myxcd * 8, 1u, RLX, AGT);
        } else {
            while (__hip_atomic_load(g + 768 + bc.myxcd * 8, RLX, AGT) == 0)
                __builtin_amdgcn_s_sleep(8);
            l1_inv();                                            // L1 only, no walk
        }
    }
    __syncthreads();
}
// Barriers 1..8: per-XCD arrival; LAST arriver on the XCD is its leader
// (its XCD is quiescent -> safe to flush immediately, overlapping others).
// Layout per barrier b (uints, base = g+1024+b*512):
//   [x*32]=xarr [256]=gdone [288+x*8]=inv-flag
static __device__ __forceinline__ void bar_sync(unsigned* g, int b, const BarCtx& bc) {
    __syncthreads();
    if (threadIdx.x == 0) {
        unsigned* base = g + 1024 + b * 512;
        __builtin_amdgcn_fence(__ATOMIC_RELEASE, "workgroup");   // drain my VMEM
        if (__hip_atomic_fetch_add(base + bc.myxcd * 32, 1u, RLX, AGT) == bc.xtot - 1u) {
            __builtin_amdgcn_fence(__ATOMIC_RELEASE, "agent");   // wbl2 (own XCD)
            __hip_atomic_fetch_add(base + 256, 1u, RLX, AGT);
            while (__hip_atomic_load(base + 256, RLX, AGT) < bc.nact)
                __builtin_amdgcn_s_sleep(8);
            __builtin_amdgcn_fence(__ATOMIC_ACQUIRE, "agent");   // L2 inv, once/XCD
            __hip_atomic_store(base + 288 + bc.myxcd * 8, 1u, RLX, AGT);
        } else {
            while (__hip_atomic_load(base + 288 + bc.myxcd * 8, RLX, AGT) == 0)
                __builtin_amdgcn_s_sleep(8);
            l1_inv();                                            // L1 only, no walk
        }
    }
    __syncthreads();
}

// ---------------------------------------------------------------------------
// Phase 0: adj -> bitmask, x -> bf16, W -> bf16 transposed, Mx init.
// ---------------------------------------------------------------------------
static __device__ __forceinline__ void do_prep(
    int blk, int tid,
    const float* __restrict__ xf, const int* __restrict__ adj,
    const float* __restrict__ W0, const float* __restrict__ W1,
    const float* __restrict__ W2,
    unsigned short* __restrict__ xc, unsigned long long* __restrict__ bits,
    unsigned short* __restrict__ W0t, unsigned short* __restrict__ W1t,
    unsigned short* __restrict__ W2t, unsigned* __restrict__ MxU)
{
    const int w = tid >> 6, lane = tid & 63;
    for (int b = blk; b < 16384; b += 512) {     // adj -> bits, 1024 elem/unit
        const int base = b * 1024 + w * 256;
        unsigned long long m[4];
#pragma unroll
        for (int r = 0; r < 4; ++r)
            m[r] = __ballot(adj[base + r * 64 + lane] != 0);
        if (lane == 0) {
            u64x2 lo = {m[0], m[1]}, hi = {m[2], m[3]};
            *(u64x2*)(bits + (base >> 6))     = lo;
            *(u64x2*)(bits + (base >> 6) + 2) = hi;
        }
    }
    for (int b = blk; b < 2048; b += 512) {      // x f32 -> bf16
        int i = b * 256 + tid;
        xc[i] = bf16_rne(xf[i]);
    }
    if (blk < 449) {                             // W transpose + Mx init
        int gid = blk * 256 + tid;
        if (gid < 32768) {                       // W0: (4,128,64)
            int h = gid >> 13, d = (gid >> 6) & 127, o = gid & 63;
            W0t[(h * 64 + o) * 128 + d] = bf16_rne(W0[gid]);
        } else if (gid < 98304) {                // W1: (4,256,64)
            int g = gid - 32768;
            int h = g >> 14, d = (g >> 6) & 255, o = g & 63;
            W1t[(h * 64 + o) * 256 + d] = bf16_rne(W1[g]);
        } else if (gid < 114688) {               // W2: (1,256,64)
            int g = gid - 98304;
            int d = g >> 6, o = g & 63;
            W2t[o * 256 + d] = bf16_rne(W2[g]);
        } else if (gid < 114700) {               // Mx[12] = encoded -inf
            MxU[gid - 114688] = 0x007FFFFFu;
        }
    }
}

// ---------------------------------------------------------------------------
// Phase G: h = X @ W (MFMA 16x16x32 bf16) -> hT[h][o][n] (bf16),
// fused el2/er2 and per-head max of er2 via encoded atomicMax.
// 64 rows per block (4 waves x 16). Active blocks: 64*H.
// ---------------------------------------------------------------------------
static __device__ __forceinline__ void do_gemm(
    int blk, int tid, int H,
    const unsigned short* __restrict__ X, int K,
    const unsigned short* __restrict__ Wt, const float* __restrict__ a,
    unsigned short* __restrict__ hT,
    float* __restrict__ el2, float* __restrict__ er2,
    unsigned* __restrict__ MxU)
{
    if (blk >= 64 * H) return;
    const int h = blk >> 6, bx = blk & 63;
    const int lane = tid & 63, w = tid >> 6;
    const int c = lane & 15, q = lane >> 4;
    const int nb = bx * 64 + w * 16;
    const unsigned short* xrow = X + (size_t)(nb + c) * K + q * 8;
    const unsigned short* wb   = Wt + ((size_t)h * 64 + c) * K + q * 8;

    f32x4 acc[4] = {{0,0,0,0},{0,0,0,0},{0,0,0,0},{0,0,0,0}};
    for (int kk = 0; kk < K; kk += 32) {
        s16x8 af = *(const s16x8*)(xrow + kk);
#pragma unroll
        for (int j = 0; j < 4; ++j) {
            s16x8 bf = *(const s16x8*)(wb + (size_t)(j * 16) * K + kk);
            acc[j] = __builtin_amdgcn_mfma_f32_16x16x32_bf16(af, bf, acc[j], 0, 0, 0);
        }
    }
    // C/D layout: col = lane&15, row = q*4 + reg  ->  hT[h][o][n]
#pragma unroll
    for (int j = 0; j < 4; ++j) {
        unsigned d0 = (unsigned)bf16_rne(acc[j][0]) | ((unsigned)bf16_rne(acc[j][1]) << 16);
        unsigned d1 = (unsigned)bf16_rne(acc[j][2]) | ((unsigned)bf16_rne(acc[j][3]) << 16);
        unsigned short* dst = hT + ((size_t)h * 64 + j * 16 + c) * 4096 + nb + q * 4;
        ((unsigned*)dst)[0] = d0;
        ((unsigned*)dst)[1] = d1;
    }
    const float* ab = a + h * 128;
    float elr[4] = {0,0,0,0}, err[4] = {0,0,0,0};
#pragma unroll
    for (int j = 0; j < 4; ++j) {
        float al = ab[j * 16 + c];
        float ar = ab[64 + j * 16 + c];
#pragma unroll
        for (int r = 0; r < 4; ++r) {
            elr[r] = fmaf(al, acc[j][r], elr[r]);
            err[r] = fmaf(ar, acc[j][r], err[r]);
        }
    }
#pragma unroll
    for (int m = 1; m <= 8; m <<= 1) {
#pragma unroll
        for (int r = 0; r < 4; ++r) {
            elr[r] += __shfl_xor(elr[r], m, 64);
            err[r] += __shfl_xor(err[r], m, 64);
        }
    }
    if (c == 0) {
#pragma unroll
        for (int r = 0; r < 4; ++r) {
            int n = nb + q * 4 + r;
            el2[h * 4096 + n] = elr[r] * LOG2E;
            er2[h * 4096 + n] = err[r] * LOG2E;
        }
    }
    float mm = fmaxf(fmaxf(err[0], err[1]), fmaxf(err[2], err[3]));
    mm = fmaxf(mm, __shfl_xor(mm, 16, 64));
    mm = fmaxf(mm, __shfl_xor(mm, 32, 64));
    if (lane == 0) {
        unsigned u = __float_as_uint(mm * LOG2E);
        unsigned key = (u & 0x80000000u) ? ~u : (u | 0x80000000u);
        atomicMax(MxU + h, key);
    }
}

// ---------------------------------------------------------------------------
// Phase A: fused masked-softmax attention, factorized exp2.
//   p[n][m] = max(Al[n]*Ar[m], Bl[n]*Br[m]) & adjbit      (p <= 1)
// SETS row-sets of 64 q-rows share each staged 64x128 key tile. Double-
// buffered global_load_lds staging (pre-swizzled source), one barrier/tile.
// ---------------------------------------------------------------------------
template <int SETS>
static __device__ __forceinline__ void do_att(
    int bx, int h, int ks, int tid,
    unsigned short (&ldsH)[2][64 * 128], float (&ldsE)[2][2][128],
    const unsigned short* __restrict__ hT,
    const float* __restrict__ el2g, const float* __restrict__ er2g,
    const unsigned* __restrict__ MxU,
    const unsigned long long* __restrict__ bits,
    float* __restrict__ accP, float* __restrict__ lP,
    int H, int KPS, int HO)
{
    const int lane = tid & 63, w = tid >> 6;
    const int c = lane & 15, q = lane >> 4, q8 = q * 8;
    const int nb = bx * (64 * SETS) + w * 16;

    unsigned kM = MxU[h];
    float M2 = __uint_as_float((kM & 0x80000000u) ? (kM & 0x7FFFFFFFu) : ~kM);

    f32x2 Av[SETS], Bv[SETS];
    const char* bitrow[SETS];
#pragma unroll
    for (int s = 0; s < SETS; ++s) {
        int rowA = nb + s * 64 + c;
        float e2 = el2g[h * 4096 + rowA];
        float xx = e2 + M2;
        float C2 = fmaxf(xx, 0.2f * xx);     // C2 >= all scores of this row
        float Al = exp2_fast(xx - C2);
        float Bl = exp2_fast(fmaf(0.2f, xx, -C2));
        Av[s] = (f32x2){Al, Al};
        Bv[s] = (f32x2){Bl, Bl};
        bitrow[s] = (const char*)bits + (size_t)rowA * 512 + (size_t)(KPS >> 3) * ks;
    }

    const unsigned short* hTh = hT + (size_t)h * 64 * 4096;
    const float* erh = er2g + h * 4096;
    const int tiles = KPS >> 7;
    const int kbase = ks * KPS;
    const int colE = tid & 127, hiE = tid >> 7;  // ldsE fill: 1 exp2/thread

    // DMA stage: LDS dest linear in lane; swizzle applied on the GLOBAL src
    // address (m173). Tile = 64 rows x 16 groups of 16B; group g at g^(o&7).
    auto STAGE = [&](int buf, int mabs_) {
#pragma unroll
        for (int i = 0; i < 4; ++i) {
            int cidx = i * 256 + tid;
            int o = cidx >> 4, g = cidx & 15;
            const unsigned short* sp =
                hTh + (size_t)o * 4096 + mabs_ + ((g ^ (o & 7)) << 3);
            unsigned short* dp = &ldsH[buf][(i * 256 + (tid & ~63)) << 3];
            __builtin_amdgcn_global_load_lds(
                (const __attribute__((address_space(1))) void*)sp,
                (__attribute__((address_space(3))) void*)dp, 16, 0, 0);
        }
    };

    s16x8 ones = {0,0,0,0,0,0,0,0};
    if (c == 0) {
#pragma unroll
        for (int i = 0; i < 8; ++i) ones[i] = (short)0x3F80;   // bf16 1.0, col 0
    }
    f32x4 acc[SETS][4];
    f32x4 accl[SETS];
#pragma unroll
    for (int s = 0; s < SETS; ++s) {
        accl[s] = (f32x4){0,0,0,0};
#pragma unroll
        for (int j = 0; j < 4; ++j) acc[s][j] = (f32x4){0,0,0,0};
    }

    // ---- prologue: stage tile 0 (DMA + column factors + bits) ----
    STAGE(0, kbase);
    {
        float ee = erh[kbase + colE] - M2;
        float xin = hiE ? 0.2f * ee : ee;
        ldsE[0][hiE][colE] = exp2_fast(xin);
    }
    i32x4 bA[SETS];
#pragma unroll
    for (int s = 0; s < SETS; ++s) bA[s] = *(const i32x4*)(bitrow[s]);
    __syncthreads();                         // drains DMA (vmcnt 0)

    for (int t = 0; t < tiles; ++t) {
        const int cur = t & 1, nxt = cur ^ 1;
        const bool more = (t + 1 < tiles);
        const unsigned short* Hc = ldsH[cur];
        const float* EcA = ldsE[cur][0];
        const float* EcB = ldsE[cur][1];

        float ern = 0.f;
        if (more) {
            const int mn = kbase + (t + 1) * 128;
            STAGE(nxt, mn);                  // async, drains at the barrier
            ern = erh[mn + colE];
        }
        int bw[SETS][4];
#pragma unroll
        for (int s = 0; s < SETS; ++s) {
            bw[s][0] = bA[s][0]; bw[s][1] = bA[s][1];
            bw[s][2] = bA[s][2]; bw[s][3] = bA[s][3];
        }
        if (more) {
#pragma unroll
            for (int s = 0; s < SETS; ++s)
                bA[s] = *(const i32x4*)(bitrow[s] + (t + 1) * 16);
        }

#pragma unroll
        for (int cc = 0; cc < 4; ++cc) {
            const int kl = cc * 32 + q8;
            const f32x4* eap = (const f32x4*)(EcA + kl);
            const f32x4* ebp = (const f32x4*)(EcB + kl);
            f32x4 eA0 = eap[0], eA1 = eap[1];      // Ar for 8 cols
            f32x4 eB0 = ebp[0], eB1 = ebp[1];      // Br for 8 cols
            const int klx = kl ^ ((c & 7) << 3);
            const unsigned short* lb = Hc + c * 128 + klx;
            s16x8 bf[4];
#pragma unroll
            for (int j = 0; j < 4; ++j)
                bf[j] = *(const s16x8*)(lb + (size_t)(j * 16) * 128);

            s16x8 af[SETS];
#pragma unroll
            for (int s = 0; s < SETS; ++s) {
                const unsigned word = (unsigned)bw[s][cc];
                unsigned pd[4];
#pragma unroll
                for (int jj = 0; jj < 4; ++jj) {
                    f32x2 ea = (jj == 0) ? eA0.xy : (jj == 1) ? eA0.zw
                             : (jj == 2) ? eA1.xy : eA1.zw;
                    f32x2 eb = (jj == 0) ? eB0.xy : (jj == 1) ? eB0.zw
                             : (jj == 2) ? eB1.xy : eB1.zw;
                    f32x2 pa = Av[s] * ea;         // v_pk_mul_f32
                    f32x2 pb = Bv[s] * eb;         // v_pk_mul_f32
                    float p0 = fmaxf(pa.x, pb.x);
                    float p1 = fmaxf(pa.y, pb.y);
                    unsigned u0 = __float_as_uint(p0) & (unsigned)sbfe1(word, q8 + 2 * jj);
                    unsigned u1 = __float_as_uint(p1) & (unsigned)sbfe1(word, q8 + 2 * jj + 1);
                    pd[jj] = pack_hi16(u1, u0);    // truncate-pack 2 bf16
                }
                union { unsigned u[4]; s16x8 s8; } afu;
                afu.u[0] = pd[0]; afu.u[1] = pd[1];
                afu.u[2] = pd[2]; afu.u[3] = pd[3];
                af[s] = afu.s8;
            }
            __builtin_amdgcn_s_setprio(1);
#pragma unroll
            for (int s = 0; s < SETS; ++s) {
#pragma unroll
                for (int j = 0; j < 4; ++j)
                    acc[s][j] = __builtin_amdgcn_mfma_f32_16x16x32_bf16(
                        af[s], bf[j], acc[s][j], 0, 0, 0);
                accl[s] = __builtin_amdgcn_mfma_f32_16x16x32_bf16(
                    af[s], ones, accl[s], 0, 0, 0);
            }
            __builtin_amdgcn_s_setprio(0);
        }

        if (more) {                          // column factors for t+1
            float ee = ern - M2;
            float xin = hiE ? 0.2f * ee : ee;
            ldsE[nxt][hiE][colE] = exp2_fast(xin);
        }
        __syncthreads();                     // one barrier/tile: drains DMA+LDS
    }

    // epilogue: denominators + partial writes per row-set
#pragma unroll
    for (int s = 0; s < SETS; ++s) {
        float ls[4];
#pragma unroll
        for (int r = 0; r < 4; ++r) ls[r] = __shfl(accl[s][r], lane & 48, 64);

        float* ap = accP + ((size_t)ks * 4096 + nb + s * 64 + q * 4) * HO + h * 64 + c;
#pragma unroll
        for (int r = 0; r < 4; ++r)
#pragma unroll
            for (int j = 0; j < 4; ++j)
                ap[(size_t)r * HO + j * 16] = acc[s][j][r];
        if (c == 0) {
#pragma unroll
            for (int r = 0; r < 4; ++r)
                lP[((size_t)ks * H + h) * 4096 + nb + s * 64 + q * 4 + r] = ls[r];
        }
    }
}

// ---------------------------------------------------------------------------
// Phase C: combine key-split partials, divide, optional ELU.
// ---------------------------------------------------------------------------
static __device__ __forceinline__ void do_comb(
    int blk, int tid,
    const float* __restrict__ accP, const float* __restrict__ lP,
    unsigned short* __restrict__ outb, float* __restrict__ outf,
    int KS, int H, int lgHO, int do_elu)
{
    const int HO = 1 << lgHO;
    const int nvb = (4096 * HO) >> 8;        // virtual 256-thread work blocks
    for (int v = blk; v < nvb; v += 512) {
        const int idx = v * 256 + tid;
        const int n = idx >> lgHO, col = idx & (HO - 1), h = col >> 6;
        float s = 0.f, l = 0.f;
        for (int ks = 0; ks < KS; ++ks) {
            s += accP[((size_t)ks * 4096 + n) * HO + col];
            l += lP[((size_t)ks * H + h) * 4096 + n];
        }
        float vv = s / l;
        if (do_elu && vv < 0.f) vv = exp2_fast(vv * LOG2E) - 1.f;
        if (outf) outf[idx] = vv;
        else      outb[idx] = bf16_rne(vv);
    }
}

// ---------------------------------------------------------------------------
// The whole 3-layer GAT as ONE plain-launch persistent kernel: 9 software
// grid barriers (hierarchical, 1 wbl2 + 1 L2-inv per XCD) replace 10
// dispatch boundaries.
// ---------------------------------------------------------------------------
__global__ __launch_bounds__(256, 2) void gat_all(
    const float* __restrict__ xf, const int* __restrict__ adj,
    const float* __restrict__ W0, const float* __restrict__ a0,
    const float* __restrict__ W1, const float* __restrict__ a1,
    const float* __restrict__ W2, const float* __restrict__ a2,
    float* __restrict__ out,
    unsigned long long* __restrict__ bits,
    unsigned short* __restrict__ hT, unsigned short* __restrict__ X12,
    unsigned short* __restrict__ Xc,
    unsigned short* __restrict__ W0t, unsigned short* __restrict__ W1t,
    unsigned short* __restrict__ W2t,
    float* __restrict__ el2, float* __restrict__ er2,
    unsigned* __restrict__ MxU,
    float* __restrict__ accP, float* __restrict__ lP,
    unsigned* __restrict__ gcnt)
{
    __shared__ unsigned short ldsH[2][64 * 128];   // 32 KB (att staging)
    __shared__ float ldsE[2][2][128];              // 2 KB  (att col factors)
    const int blk = blockIdx.x, tid = threadIdx.x;

    BarCtx bc;
    if (tid == 0) bar_register(gcnt, bc);          // xtot[myxcd]++ at entry

    do_prep(blk, tid, xf, adj, W0, W1, W2, Xc, bits, W0t, W1t, W2t, MxU);
    bar_sync0(gcnt, bc);

    // layer 0: K=128, H=4
    do_gemm(blk, tid, 4, Xc, 128, W0t, a0, hT, el2, er2, MxU + 0);
    bar_sync(gcnt, 1, bc);
    do_att<2>(blk & 31, (blk >> 5) & 3, blk >> 7, tid, ldsH, ldsE,
              hT, el2, er2, MxU + 0, bits, accP, lP, 4, 1024, 256);
    bar_sync(gcnt, 2, bc);
    do_comb(blk, tid, accP, lP, X12, nullptr, 4, 4, 8, 1);
    bar_sync(gcnt, 3, bc);

    // layer 1: K=256, H=4
    do_gemm(blk, tid, 4, X12, 256, W1t, a1, hT, el2, er2, MxU + 4);
    bar_sync(gcnt, 4, bc);
    do_att<2>(blk & 31, (blk >> 5) & 3, blk >> 7, tid, ldsH, ldsE,
              hT, el2, er2, MxU + 4, bits, accP, lP, 4, 1024, 256);
    bar_sync(gcnt, 5, bc);
    do_comb(blk, tid, accP, lP, X12, nullptr, 4, 4, 8, 1);
    bar_sync(gcnt, 6, bc);

    // layer 2: K=256, H=1, output f32 (no ELU)
    do_gemm(blk, tid, 1, X12, 256, W2t, a2, hT, el2, er2, MxU + 8);
    bar_sync(gcnt, 7, bc);
    do_att<1>(blk & 63, 0, blk >> 6, tid, ldsH, ldsE,
              hT, el2, er2, MxU + 8, bits, accP, lP, 1, 512, 64);
    bar_sync(gcnt, 8, bc);
    do_comb(blk, tid, accP, lP, nullptr, out, 8, 1, 6, 0);
}

// ---------------------------------------------------------------------------
extern "C" void kernel_launch(void* const* d_in, const int* in_sizes, int n_in,
                              void* d_out, int out_size, void* d_ws, size_t ws_size,
                              hipStream_t stream)
{
    (void)in_sizes; (void)n_in; (void)out_size; (void)ws_size;
    const float* x   = (const float*)d_in[0];
    const int*   adj = (const int*)d_in[1];
    const float* W0  = (const float*)d_in[2];
    const float* a0  = (const float*)d_in[3];
    const float* W1  = (const float*)d_in[4];
    const float* a1  = (const float*)d_in[5];
    const float* W2  = (const float*)d_in[6];
    const float* a2  = (const float*)d_in[7];

    char* p = (char*)d_ws;                                   // ~25 MB used
    unsigned long long* bits = (unsigned long long*)(p + 0x000000);  // 2 MB
    unsigned short* hT  = (unsigned short*)(p + 0x200000);           // 2 MB
    unsigned short* X12 = (unsigned short*)(p + 0x400000);           // 2 MB
    unsigned short* Xc  = (unsigned short*)(p + 0x600000);           // 1 MB
    unsigned short* W0t = (unsigned short*)(p + 0x700000);           // 64 KB
    unsigned short* W1t = (unsigned short*)(p + 0x710000);           // 128 KB
    unsigned short* W2t = (unsigned short*)(p + 0x730000);           // 32 KB
    float*    el2  = (float*)(p + 0x738000);                         // 64 KB
    float*    er2  = (float*)(p + 0x748000);                         // 64 KB
    unsigned* MxU  = (unsigned*)(p + 0x758000);                      // 48 B
    float*    accP = (float*)(p + 0x760000);                         // 16 MB
    float*    lP   = (float*)(p + 0x1760000);                        // 256 KB
    unsigned* gcnt = (unsigned*)(p + 0x17A0000);                     // 32 KB

    // zero barrier state (garr/gdone/xled/xtot/xarr/flags), per replay
    hipMemsetAsync(gcnt, 0, 0x8000, stream);

    gat_all<<<GRID_BLOCKS, 256, 0, stream>>>(
        x, adj, W0, a0, W1, a1, W2, a2, (float*)d_out,
        bits, hT, X12, Xc, W0t, W1t, W2t, el2, er2, MxU, accP, lP, gcnt);
}